// Round 2
// baseline (1283.187 us; speedup 1.0000x reference)
//
#include <hip/hip_runtime.h>
#include <hip/hip_bf16.h>
#include <math.h>

// Problem constants
#define B_ 8
#define Q_ 200
#define K_ 16384
#define D_ 256
#define H_ 8
#define DH_ 32
#define ALIGNK_ 96
#define CROSSK_ 1024
#define FF_ 1024
#define BQ_ (B_*Q_)     // 1600
#define BK_ (B_*K_)     // 131072

typedef unsigned short u16;
typedef short bf16x8 __attribute__((ext_vector_type(8)));
typedef float f32x4 __attribute__((ext_vector_type(4)));

__device__ __forceinline__ float b2f(u16 u){ return __uint_as_float(((unsigned)u)<<16); }
__device__ __forceinline__ u16 f2b(float f){
  unsigned x = __float_as_uint(f);
  unsigned r = x + 0x7FFFu + ((x>>16)&1u);   // round-to-nearest-even
  return (u16)(r>>16);
}
__device__ __forceinline__ unsigned p2u(float lo, float hi){
  return (unsigned)f2b(lo) | ((unsigned)f2b(hi)<<16);
}
__device__ __forceinline__ uint4 pk8(float4 a, float4 b){
  return make_uint4(p2u(a.x,a.y), p2u(a.z,a.w), p2u(b.x,b.y), p2u(b.z,b.w));
}
// order-preserving float->uint key (larger float => larger key)
__device__ __forceinline__ unsigned fkey(float f){ unsigned b=__float_as_uint(f); return (b&0x80000000u)? ~b : (b|0x80000000u); }
__device__ __forceinline__ float funkey(unsigned k){ unsigned b=(k&0x80000000u)? (k^0x80000000u) : ~k; return __uint_as_float(b); }
__device__ __forceinline__ float gelu_f(float x){ return 0.5f*x*(1.0f+erff(x*0.70710678118654752f)); }
__device__ __forceinline__ float sigmoid_f(float x){ return 1.0f/(1.0f+__expf(-x)); }

// ---------------------------------------------------------------------------
// General NT GEMM:  C[m,n] = sum_k A[m,k]*B[n,k]  (fp32 acc). A/B each either
// fp32 (converted to bf16 in registers) or bf16. Tile 64x64, BK=64, 4 waves.
// Modes: optional fp32 bias[n], act (1=gelu,2=sigmoid), out fp32 or bf16,
//        per-column atomic-max (importance), optional A-row gather.
// ---------------------------------------------------------------------------
struct GArgs {
  const void* A; const void* B; const float* bias;
  float* Cf; u16* Cb; unsigned* amax;
  const int* gather;
  long lda, ldb, ldc;
  long sA, sB, sC, sAmax, sGather;
  int M, N, K, act;
};

template<int AF32, int BF32>
__global__ __launch_bounds__(256) void gemm_bt(GArgs g)
{
  const int tid = threadIdx.x;
  const int bz = blockIdx.z;
  const int m0 = blockIdx.y*64, n0 = blockIdx.x*64;
  const int lane = tid & 63, wave = tid >> 6;
  const int wr = wave >> 1, wc = wave & 1;
  __shared__ __align__(16) u16 As[64][72];
  __shared__ __align__(16) u16 Bs[64][72];
  f32x4 acc[2][2] = {};

  const int lrow = tid>>2;
  const int lk = (tid&3)*16;
  int ar = m0 + lrow; if (ar > g.M-1) ar = g.M-1;
  if (g.gather) ar = g.gather[(long)bz*g.sGather + ar];
  int br = n0 + lrow; if (br > g.N-1) br = g.N-1;
  long aoff = (long)bz*g.sA + (long)ar*g.lda + lk;
  long boff = (long)bz*g.sB + (long)br*g.ldb + lk;

  const int nk = g.K >> 6;
  for (int kt=0; kt<nk; ++kt){
    uint4 wa0, wa1, wb0, wb1;
    if (AF32){
      const float* p = (const float*)g.A + aoff;
      float4 f0 = *(const float4*)(p+0);
      float4 f1 = *(const float4*)(p+4);
      float4 f2v= *(const float4*)(p+8);
      float4 f3 = *(const float4*)(p+12);
      wa0 = pk8(f0,f1); wa1 = pk8(f2v,f3);
    } else {
      const u16* p = (const u16*)g.A + aoff;
      wa0 = *(const uint4*)p; wa1 = *(const uint4*)(p+8);
    }
    if (BF32){
      const float* p = (const float*)g.B + boff;
      float4 f0 = *(const float4*)(p+0);
      float4 f1 = *(const float4*)(p+4);
      float4 f2v= *(const float4*)(p+8);
      float4 f3 = *(const float4*)(p+12);
      wb0 = pk8(f0,f1); wb1 = pk8(f2v,f3);
    } else {
      const u16* p = (const u16*)g.B + boff;
      wb0 = *(const uint4*)p; wb1 = *(const uint4*)(p+8);
    }
    aoff += 64; boff += 64;
    __syncthreads();
    *(uint4*)&As[lrow][lk]   = wa0; *(uint4*)&As[lrow][lk+8] = wa1;
    *(uint4*)&Bs[lrow][lk]   = wb0; *(uint4*)&Bs[lrow][lk+8] = wb1;
    __syncthreads();
    #pragma unroll
    for (int kk=0; kk<2; ++kk){
      const int ko = kk*32 + (lane>>4)*8;
      bf16x8 af0 = *(const bf16x8*)&As[wr*32      + (lane&15)][ko];
      bf16x8 af1 = *(const bf16x8*)&As[wr*32 + 16 + (lane&15)][ko];
      bf16x8 bf0 = *(const bf16x8*)&Bs[wc*32      + (lane&15)][ko];
      bf16x8 bf1 = *(const bf16x8*)&Bs[wc*32 + 16 + (lane&15)][ko];
      acc[0][0] = __builtin_amdgcn_mfma_f32_16x16x32_bf16(af0, bf0, acc[0][0], 0,0,0);
      acc[0][1] = __builtin_amdgcn_mfma_f32_16x16x32_bf16(af0, bf1, acc[0][1], 0,0,0);
      acc[1][0] = __builtin_amdgcn_mfma_f32_16x16x32_bf16(af1, bf0, acc[1][0], 0,0,0);
      acc[1][1] = __builtin_amdgcn_mfma_f32_16x16x32_bf16(af1, bf1, acc[1][1], 0,0,0);
    }
  }

  if (g.amax){
    // per-column max over rows (M-clamp duplicates a valid row -> max unaffected)
    #pragma unroll
    for (int j=0;j<2;j++){
      float mx = -3.0e38f;
      #pragma unroll
      for (int i=0;i<2;i++)
        #pragma unroll
        for (int r=0;r<4;r++) mx = fmaxf(mx, acc[i][j][r]);
      mx = fmaxf(mx, __shfl_xor(mx, 16));
      mx = fmaxf(mx, __shfl_xor(mx, 32));
      if ((lane>>4)==0){
        int n = n0 + wc*32 + j*16 + (lane&15);
        if (n < g.N) atomicMax(&g.amax[(long)bz*g.sAmax + n], fkey(mx));
      }
    }
    return;
  }

  #pragma unroll
  for (int i=0;i<2;i++)
  #pragma unroll
  for (int j=0;j<2;j++)
  #pragma unroll
  for (int r=0;r<4;r++){
    int m = m0 + wr*32 + i*16 + (lane>>4)*4 + r;   // C row = quad*4+reg
    int n = n0 + wc*32 + j*16 + (lane&15);          // C col = lane&15
    if (m < g.M && n < g.N){
      float v = acc[i][j][r];
      if (g.bias) v += g.bias[n];
      if (g.act==1) v = gelu_f(v);
      else if (g.act==2) v = sigmoid_f(v);
      long ci = (long)bz*g.sC + (long)m*g.ldc + n;
      if (g.Cf) g.Cf[ci] = v; else g.Cb[ci] = f2b(v);
    }
  }
}

// ---------------------------------------------------------------------------
// In-place row l2-normalize (D=256, bf16), x /= max(||x||,1e-6). 4 rows/block.
// ---------------------------------------------------------------------------
__global__ __launch_bounds__(256) void l2norm_rows(u16* x, int rows)
{
  int row = blockIdx.x*4 + (threadIdx.x>>6);
  int lane = threadIdx.x & 63;
  if (row >= rows) return;
  u16* p = x + (long)row*256;
  float v[4]; float s = 0.f;
  #pragma unroll
  for (int i=0;i<4;i++){ v[i] = b2f(p[lane + i*64]); s += v[i]*v[i]; }
  #pragma unroll
  for (int off=32; off; off>>=1) s += __shfl_xor(s, off);
  float inv = 1.0f / fmaxf(sqrtf(s), 1e-6f);
  #pragma unroll
  for (int i=0;i<4;i++) p[lane + i*64] = f2b(v[i]*inv);
}

// ---------------------------------------------------------------------------
// Exact top-RANK of a 16384-long row. Bitwise rank-select on order-preserving
// keys + index tie-break (smallest indices first) == jax.lax.top_k's set.
// ---------------------------------------------------------------------------
__global__ __launch_bounds__(256) void topk_kernel(const float* inF, const unsigned* inK,
    long in_stride, int RANK, float* out_val, int* out_idx)
{
  __shared__ int red[4];
  __shared__ int poss;
  int row = blockIdx.x, tid = threadIdx.x;
  unsigned kr[64];
  if (inF){
    const float* p = inF + (long)row*in_stride;
    #pragma unroll
    for (int j=0;j<64;j++) kr[j] = fkey(p[tid + j*256]);
  } else {
    const unsigned* p = inK + (long)row*in_stride;
    #pragma unroll
    for (int j=0;j<64;j++) kr[j] = p[tid + j*256];
  }
  if (tid==0) poss = 0;

  unsigned u = 0;
  for (int bit=31; bit>=0; --bit){
    unsigned cand = u | (1u<<bit);
    int c = 0;
    #pragma unroll
    for (int j=0;j<64;j++) c += (kr[j] >= cand) ? 1 : 0;
    for (int off=32; off; off>>=1) c += __shfl_down(c, off);
    __syncthreads();
    if ((tid&63)==0) red[tid>>6] = c;
    __syncthreads();
    c = red[0]+red[1]+red[2]+red[3];
    if (c >= RANK) u = cand;
  }
  int cgt = 0;
  #pragma unroll
  for (int j=0;j<64;j++) cgt += (kr[j] > u) ? 1 : 0;
  for (int off=32; off; off>>=1) cgt += __shfl_down(cgt, off);
  __syncthreads();
  if ((tid&63)==0) red[tid>>6] = cgt;
  __syncthreads();
  cgt = red[0]+red[1]+red[2]+red[3];
  int Req = RANK - cgt;   // >=1 always
  int t = 0;
  for (int bit=13; bit>=0; --bit){
    int cand = t | (1<<bit);
    int c = 0;
    #pragma unroll
    for (int j=0;j<64;j++) c += (kr[j]==u && (tid + j*256) < cand) ? 1 : 0;
    for (int off=32; off; off>>=1) c += __shfl_down(c, off);
    __syncthreads();
    if ((tid&63)==0) red[tid>>6] = c;
    __syncthreads();
    c = red[0]+red[1]+red[2]+red[3];
    if (c < Req) t = cand;
  }
  __syncthreads();
  #pragma unroll
  for (int j=0;j<64;j++){
    int e = tid + j*256;
    unsigned kk = kr[j];
    if (kk > u || (kk == u && e <= t)){
      int p2 = atomicAdd(&poss, 1);
      out_val[(long)row*RANK + p2] = funkey(kk);
      out_idx[(long)row*RANK + p2] = e;
    }
  }
}

// ---------------------------------------------------------------------------
// aligned[row,:] = softmax(vals96) . memory[b, idx96, :]   (memory fp32)
// ---------------------------------------------------------------------------
__global__ __launch_bounds__(256) void align_combine(const float* vals, const int* idx,
    const float* memory, float* alignedv)
{
  __shared__ float w[96];
  __shared__ int id[96];
  __shared__ float reds[2];
  int row = blockIdx.x, tid = threadIdx.x;
  int b = row / 200;
  if (tid < 96){ w[tid] = vals[(long)row*96 + tid]; id[tid] = idx[(long)row*96 + tid]; }
  __syncthreads();
  if (tid < 64){
    float a = w[tid];
    float bb2 = (tid < 32) ? w[64+tid] : -3e38f;
    float m = fmaxf(a, bb2);
    #pragma unroll
    for (int off=32; off; off>>=1) m = fmaxf(m, __shfl_xor(m, off));
    if (tid==0) reds[0] = m;
  }
  __syncthreads();
  float m = reds[0];
  if (tid < 96) w[tid] = __expf(w[tid]-m);
  __syncthreads();
  if (tid < 64){
    float a = w[tid] + ((tid<32)? w[64+tid] : 0.f);
    #pragma unroll
    for (int off=32; off; off>>=1) a += __shfl_xor(a, off);
    if (tid==0) reds[1] = a;
  }
  __syncthreads();
  float invs = 1.0f/reds[1];
  float acc = 0.f;
  const float* mb = memory + (long)b*K_*D_;
  for (int k=0;k<96;k++) acc += w[k] * mb[(long)id[k]*D_ + tid];
  alignedv[(long)row*256 + tid] = acc*invs;
}

__global__ void make_cat(const float* q, const float* alignedv, u16* cat)
{
  int row = blockIdx.x, tid = threadIdx.x;
  long i = (long)row*256 + tid;
  cat[(long)row*512 + tid]       = f2b(q[i]);
  cat[(long)row*512 + 256 + tid] = f2b(alignedv[i]);
}

__global__ void combine_gate(const float* q, const float* q_pos, const float* alignedv,
    const float* gate, float* qx, u16* qx_b, u16* qk_b)
{
  int row = blockIdx.x, tid = threadIdx.x;
  long i = (long)row*256 + tid;
  float v = q[i] + gate[i]*alignedv[i];
  qx[i] = v;
  qx_b[i] = f2b(v);
  qk_b[i] = f2b(v + q_pos[i]);
}

// ---------------------------------------------------------------------------
// t = x + y; LN over D=256 (biased var, eps 1e-5). Optional outputs.
// fminf/fmaxf launder NaN (return the non-NaN operand) -> finite diagnostics.
// ---------------------------------------------------------------------------
__global__ __launch_bounds__(256) void add_ln(const float* x, const float* y,
    const float* g, const float* bb, const float* q_pos,
    float* out_f, u16* out_b, u16* out_pos_b)
{
  __shared__ float red[8];
  int row = blockIdx.x, tid = threadIdx.x;
  long i = (long)row*256 + tid;
  float t = fminf(fmaxf(x[i] + y[i], -1e6f), 1e6f);
  float s1 = t, s2 = t*t;
  #pragma unroll
  for (int off=32; off; off>>=1){ s1 += __shfl_down(s1,off); s2 += __shfl_down(s2,off); }
  if ((tid&63)==0){ red[(tid>>6)*2] = s1; red[(tid>>6)*2+1] = s2; }
  __syncthreads();
  s1 = red[0]+red[2]+red[4]+red[6];
  s2 = red[1]+red[3]+red[5]+red[7];
  float mu = s1 * (1.0f/256.0f);
  float var = fmaxf(s2 * (1.0f/256.0f) - mu*mu, 0.f);
  float rstd = rsqrtf(var + 1e-5f);
  float v = (t-mu)*rstd*g[tid] + bb[tid];
  if (out_f) out_f[i] = v;
  if (out_b) out_b[i] = f2b(v);
  if (out_pos_b) out_pos_b[i] = f2b(v + q_pos[i]);
}

__global__ void fill_u32(unsigned* p, unsigned val, int n)
{ int i = blockIdx.x*256 + threadIdx.x; if (i<n) p[i] = val; }

// ---------------------------------------------------------------------------
// Fused MHA, flash-style with KV-split (flash-decoding). One block per
// (b, h, 64-q-tile, kv-split). Scores kept in registers (no Ps LDS);
// each thread accumulates all 32 dims for its q-row quadrant, quad-reduced
// via shfl at the end. Partial (o, m, l) written fp32; combined separately.
// LDS: 2*64*36*4 = 18.4 KB -> ~8 blocks/CU by LDS (grid gives ~4).
// ---------------------------------------------------------------------------
__global__ __launch_bounds__(256) void attn_kernel(
    const u16* Qb, int q_stride,
    const u16* KVb, int kv_stride, int k_off, int v_off, int Lk,
    const float* bias, const int* kidx,
    int nsplit, int chunk,
    float* opart, float* mlpart, float scale)
{
  __shared__ float Ks[64][36];
  __shared__ float Vs[64][36];
  __shared__ int kid_s[64];
  const int b = blockIdx.z, h = blockIdx.y;
  const int split = blockIdx.x % nsplit;
  const int q0 = (blockIdx.x / nsplit) * 64;
  const int tid = threadIdx.x;
  const int cg = tid & 3, r = tid >> 2;
  const int kbeg = split*chunk;
  int kend = kbeg + chunk; if (kend > Lk) kend = Lk;

  int qr = q0 + r; if (qr > 199) qr = 199;
  float qreg[32];
  {
    const u16* qp = Qb + (long)(b*200+qr)*q_stride + h*32;
    #pragma unroll
    for (int w=0; w<4; w++){
      uint4 u = *(const uint4*)(qp + w*8);
      qreg[w*8+0]=b2f((u16)(u.x&0xffffu))*scale; qreg[w*8+1]=b2f((u16)(u.x>>16))*scale;
      qreg[w*8+2]=b2f((u16)(u.y&0xffffu))*scale; qreg[w*8+3]=b2f((u16)(u.y>>16))*scale;
      qreg[w*8+4]=b2f((u16)(u.z&0xffffu))*scale; qreg[w*8+5]=b2f((u16)(u.z>>16))*scale;
      qreg[w*8+6]=b2f((u16)(u.w&0xffffu))*scale; qreg[w*8+7]=b2f((u16)(u.w>>16))*scale;
    }
  }
  const long bias_row = ((long)(b*200 + qr))*(long)K_;

  float o32[32];
  #pragma unroll
  for (int i=0;i<32;i++) o32[i]=0.f;
  float mrun = -3e38f, lrun = 0.f;

  const int srow = tid>>2, sc8 = (tid&3)*8;   // staging: 1 uint4 per matrix
  for (int j0=kbeg; j0<kend; j0+=64){
    // issue global loads early (overlap with prior tile's LDS reads)
    int kr = j0 + srow; if (kr > kend-1) kr = kend-1;
    const long base = (long)(b*Lk + kr)*kv_stride;
    uint4 ku = *(const uint4*)(KVb + base + k_off + sc8);
    uint4 vu = *(const uint4*)(KVb + base + v_off + sc8);
    int kdreg = 0;
    if (kidx && tid < 64){ int kk = j0 + tid; if (kk > Lk-1) kk = Lk-1; kdreg = kidx[b*CROSSK_ + kk]; }
    __syncthreads();   // prior tile fully consumed
    if (kidx && tid < 64) kid_s[tid] = kdreg;
    {
      float4 f0, f1;
      f0.x=b2f((u16)(ku.x&0xffffu)); f0.y=b2f((u16)(ku.x>>16)); f0.z=b2f((u16)(ku.y&0xffffu)); f0.w=b2f((u16)(ku.y>>16));
      f1.x=b2f((u16)(ku.z&0xffffu)); f1.y=b2f((u16)(ku.z>>16)); f1.z=b2f((u16)(ku.w&0xffffu)); f1.w=b2f((u16)(ku.w>>16));
      *(float4*)&Ks[srow][sc8] = f0; *(float4*)&Ks[srow][sc8+4] = f1;
      f0.x=b2f((u16)(vu.x&0xffffu)); f0.y=b2f((u16)(vu.x>>16)); f0.z=b2f((u16)(vu.y&0xffffu)); f0.w=b2f((u16)(vu.y>>16));
      f1.x=b2f((u16)(vu.z&0xffffu)); f1.y=b2f((u16)(vu.z>>16)); f1.z=b2f((u16)(vu.w&0xffffu)); f1.w=b2f((u16)(vu.w>>16));
      *(float4*)&Vs[srow][sc8] = f0; *(float4*)&Vs[srow][sc8+4] = f1;
    }
    __syncthreads();

    float sv[16];
    float mloc = -3e38f;
    #pragma unroll
    for (int jj=0;jj<16;jj++){
      const int c = cg + jj*4;
      const float4* kp = (const float4*)&Ks[c][0];
      float a = 0.f;
      #pragma unroll
      for (int dq=0;dq<8;dq++){
        float4 kv = kp[dq];
        a += qreg[dq*4+0]*kv.x + qreg[dq*4+1]*kv.y + qreg[dq*4+2]*kv.z + qreg[dq*4+3]*kv.w;
      }
      if (kidx) a += bias[bias_row + kid_s[c]];
      if (j0 + c >= kend) a = -3e38f;
      sv[jj] = a; mloc = fmaxf(mloc, a);
    }
    mloc = fmaxf(mloc, __shfl_xor(mloc,1));
    mloc = fmaxf(mloc, __shfl_xor(mloc,2));
    const float mnew = fmaxf(mrun, mloc);
    const float alpha = __expf(mrun - mnew);
    float lloc = 0.f;
    #pragma unroll
    for (int jj=0;jj<16;jj++){
      float p = (j0 + cg + jj*4 >= kend) ? 0.f : __expf(sv[jj]-mnew);
      sv[jj] = p; lloc += p;
    }
    lloc += __shfl_xor(lloc,1);
    lloc += __shfl_xor(lloc,2);
    lrun = lrun*alpha + lloc;
    #pragma unroll
    for (int i=0;i<32;i++) o32[i] *= alpha;
    #pragma unroll
    for (int jj=0;jj<16;jj++){
      const int c = cg + jj*4;
      const float p = sv[jj];
      const float4* vp = (const float4*)&Vs[c][0];
      #pragma unroll
      for (int dq=0;dq<8;dq++){
        float4 v = vp[dq];
        o32[dq*4+0] += p*v.x; o32[dq*4+1] += p*v.y; o32[dq*4+2] += p*v.z; o32[dq*4+3] += p*v.w;
      }
    }
    mrun = mnew;
  }

  // reduce across the quad (lanes xor 1, 2) -> full sums on all 4 lanes
  #pragma unroll
  for (int d=0;d<32;d++){
    float v = o32[d];
    v += __shfl_xor(v,1);
    v += __shfl_xor(v,2);
    o32[d] = v;
  }
  if (q0 + r < 200){
    const long pbase = (((long)(b*H_+h)*nsplit + split)*200) + (q0 + r);
    float* op = opart + pbase*32;
    #pragma unroll
    for (int i=0;i<8;i++) op[cg*8+i] = o32[cg*8+i];
    if (cg==0){ mlpart[pbase*2] = mrun; mlpart[pbase*2+1] = lrun; }
  }
}

// Combine KV-split partials: out = sum_s o_s*exp(m_s-M) / sum_s l_s*exp(m_s-M)
__global__ __launch_bounds__(256) void attn_combine(const float* opart, const float* mlpart,
    int nsplit, u16* outp)
{
  int row = blockIdx.x;                 // 0..BQ_-1
  int b = row/200, qi = row%200;
  int tid = threadIdx.x;
  int h = tid>>5, d = tid&31;
  const long base = ((long)(b*H_+h)*nsplit)*200 + qi;   // + s*200 per split
  float M = -3e38f;
  for (int s=0;s<nsplit;s++) M = fmaxf(M, mlpart[(base + (long)s*200)*2]);
  float L = 0.f, acc = 0.f;
  for (int s=0;s<nsplit;s++){
    const long ix = base + (long)s*200;
    float w = __expf(mlpart[ix*2] - M);
    L   += mlpart[ix*2+1]*w;
    acc += opart[ix*32 + d]*w;
  }
  outp[(long)row*256 + h*32 + d] = f2b(acc / fmaxf(L, 1e-30f));
}

// ---------------------------------------------------------------------------
extern "C" void kernel_launch(void* const* d_in, const int* in_sizes, int n_in,
                              void* d_out, int out_size, void* d_ws, size_t ws_size,
                              hipStream_t stream)
{
  const float* q        = (const float*)d_in[0];
  const float* q_pos    = (const float*)d_in[1];
  const float* memory   = (const float*)d_in[2];
  const float* cbias    = (const float*)d_in[3];
  const float* align_wq = (const float*)d_in[4];
  const float* align_wm = (const float*)d_in[5];
  const float* gate_w1  = (const float*)d_in[6];
  const float* gate_b1  = (const float*)d_in[7];
  const float* gate_w2  = (const float*)d_in[8];
  const float* gate_b2  = (const float*)d_in[9];
  const float* cross_wq = (const float*)d_in[10];
  const float* cross_wm = (const float*)d_in[11];
  const float* sa_in_w  = (const float*)d_in[12];
  const float* sa_in_b  = (const float*)d_in[13];
  const float* sa_out_w = (const float*)d_in[14];
  const float* sa_out_b = (const float*)d_in[15];
  const float* ca_in_w  = (const float*)d_in[16];
  const float* ca_in_b  = (const float*)d_in[17];
  const float* ca_out_w = (const float*)d_in[18];
  const float* ca_out_b = (const float*)d_in[19];
  const float* ffn_w1   = (const float*)d_in[20];
  const float* ffn_b1   = (const float*)d_in[21];
  const float* ffn_w2   = (const float*)d_in[22];
  const float* ffn_b2   = (const float*)d_in[23];
  const float* n1_g = (const float*)d_in[24];
  const float* n1_b = (const float*)d_in[25];
  const float* n2_g = (const float*)d_in[26];
  const float* n2_b = (const float*)d_in[27];
  const float* n3_g = (const float*)d_in[28];
  const float* n3_b = (const float*)d_in[29];
  float* out = (float*)d_out;   // reference output dtype is fp32

  // ---- workspace layout, fitted to ws_size (deterministic per call) ----
  char* wsb = (char*)d_ws;
  size_t off = 0;
  auto alloc = [&](size_t bytes)->char*{
    char* p = wsb + off; off = (off + bytes + 255) & ~(size_t)255; return p;
  };
  const int NSPLIT = 4;   // KV splits for both attentions
  // small fixed buffers (~29 MB)
  u16*    qn_bf   = (u16*)   alloc((size_t)BQ_*D_*2);
  float*  vals96  = (float*) alloc((size_t)BQ_*96*4);
  int*    idx96   = (int*)   alloc((size_t)BQ_*96*4);
  float*  alignedv= (float*) alloc((size_t)BQ_*D_*4);
  u16*    cat_bf  = (u16*)   alloc((size_t)BQ_*512*2);
  u16*    h_bf    = (u16*)   alloc((size_t)BQ_*D_*2);
  float*  gatebuf = (float*) alloc((size_t)BQ_*D_*4);
  float*  qx      = (float*) alloc((size_t)BQ_*D_*4);
  u16*    qx_bf   = (u16*)   alloc((size_t)BQ_*D_*2);
  u16*    qk_bf   = (u16*)   alloc((size_t)BQ_*D_*2);
  u16*    qpos2_bf= (u16*)   alloc((size_t)BQ_*D_*2);
  u16*    qkv_bf  = (u16*)   alloc((size_t)BQ_*768*2);
  u16*    attO_bf = (u16*)   alloc((size_t)BQ_*D_*2);
  float*  q2      = (float*) alloc((size_t)BQ_*D_*4);
  unsigned* imp   = (unsigned*)alloc((size_t)B_*K_*4);
  int*    kidx    = (int*)   alloc((size_t)B_*CROSSK_*4);
  u16*    cq_bf   = (u16*)   alloc((size_t)BQ_*D_*2);
  u16*    f1_bf   = (u16*)   alloc((size_t)BQ_*FF_*2);
  float*  f2buf   = (float*) alloc((size_t)BQ_*D_*4);
  float*  opart   = (float*) alloc((size_t)B_*H_*NSPLIT*200*32*4);  // 6.6 MB
  float*  mlpart  = (float*) alloc((size_t)B_*H_*NSPLIT*200*2*4);   // 0.4 MB

  // big buffers: mn (>= kvbuf size, kvbuf aliases it) and simbuf
  const size_t kv_bytes   = (size_t)B_*CROSSK_*512*2;        // 8.4 MB
  const size_t mn_full    = (size_t)BK_*D_*2;                // 67 MB
  const size_t mn_small   = (size_t)K_*D_*2;                 // 8.4 MB
  const size_t sim_full   = (size_t)BQ_*K_*4;                // 105 MB
  size_t remain = (ws_size > off) ? ws_size - off : 0;
  bool fullws = remain >= mn_full + sim_full + (1u<<20);
  size_t mn_bytes = fullws ? mn_full : (mn_small > kv_bytes ? mn_small : kv_bytes);
  int simRows;                      // rows of sim materialized at once
  if (fullws) simRows = BQ_;
  else {
    size_t left = (remain > mn_bytes + (1u<<18)) ? remain - mn_bytes - (1u<<18) : 0;
    long r = (long)(left / ((size_t)K_*4));
    simRows = (int)(r < 8 ? 8 : (r > Q_ ? Q_ : r));
  }
  u16*   mn_bf  = (u16*)  alloc(mn_bytes);
  u16*   kvbuf  = (u16*)  mn_bf;     // alias: mn dead before kvbuf is written
  float* simbuf = (float*)alloc((size_t)simRows*K_*4);

  auto gemm = [&](int af32, int bf32,
                  const void* A, long lda, long sA,
                  const void* Bm, long ldb, long sB,
                  int M, int N, int Kd,
                  const float* bias, int act,
                  float* Cf, u16* Cb, long ldc, long sC,
                  unsigned* amax, long sAmax,
                  const int* gather, long sGather, int Z){
    GArgs ga;
    ga.A=A; ga.B=Bm; ga.bias=bias; ga.Cf=Cf; ga.Cb=Cb; ga.amax=amax; ga.gather=gather;
    ga.lda=lda; ga.ldb=ldb; ga.ldc=ldc; ga.sA=sA; ga.sB=sB; ga.sC=sC;
    ga.sAmax=sAmax; ga.sGather=sGather;
    ga.M=M; ga.N=N; ga.K=Kd; ga.act=act;
    dim3 grid(N/64, (M+63)/64, Z);
    if (af32 && bf32)      gemm_bt<1,1><<<grid, 256, 0, stream>>>(ga);
    else if (af32)         gemm_bt<1,0><<<grid, 256, 0, stream>>>(ga);
    else if (bf32)         gemm_bt<0,1><<<grid, 256, 0, stream>>>(ga);
    else                   gemm_bt<0,0><<<grid, 256, 0, stream>>>(ga);
  };
  const float ascale = 0.17677669529663687f;  // 1/sqrt(32)

  // --- align: projections + l2norm + sim + top-96 ---
  gemm(1,1, q,256,0, align_wq,256,0, BQ_,256,256, nullptr,0, nullptr,qn_bf,256,0, nullptr,0, nullptr,0, 1);
  l2norm_rows<<<BQ_/4,256,0,stream>>>(qn_bf, BQ_);
  if (fullws){
    gemm(1,1, memory,256,0, align_wm,256,0, BK_,256,256, nullptr,0, nullptr,mn_bf,256,0, nullptr,0, nullptr,0, 1);
    l2norm_rows<<<BK_/4,256,0,stream>>>(mn_bf, BK_);
    gemm(0,0, qn_bf,256,(long)200*256, mn_bf,256,(long)K_*256, 200,K_,256,
         nullptr,0, simbuf,nullptr,K_,(long)200*K_, nullptr,0, nullptr,0, B_);
    topk_kernel<<<BQ_,256,0,stream>>>(simbuf, nullptr, K_, 96, vals96, idx96);
  } else {
    for (int b=0;b<B_;b++){
      gemm(1,1, memory + (size_t)b*K_*256,256,0, align_wm,256,0, K_,256,256,
           nullptr,0, nullptr,mn_bf,256,0, nullptr,0, nullptr,0, 1);
      l2norm_rows<<<K_/4,256,0,stream>>>(mn_bf, K_);
      for (int q0=0; q0<Q_; q0+=simRows){
        int rows = (Q_ - q0 < simRows) ? (Q_ - q0) : simRows;
        gemm(0,0, qn_bf + ((size_t)b*200+q0)*256,256,0, mn_bf,256,0, rows,K_,256,
             nullptr,0, simbuf,nullptr,K_,0, nullptr,0, nullptr,0, 1);
        topk_kernel<<<rows,256,0,stream>>>(simbuf, nullptr, K_, 96,
             vals96 + ((size_t)b*200+q0)*96, idx96 + ((size_t)b*200+q0)*96);
      }
    }
  }
  align_combine<<<BQ_,256,0,stream>>>(vals96, idx96, memory, alignedv);

  // --- gate MLP ---
  make_cat<<<BQ_,256,0,stream>>>(q, alignedv, cat_bf);
  gemm(0,1, cat_bf,512,0, gate_w1,512,0, BQ_,256,512, gate_b1,1, nullptr,h_bf,256,0, nullptr,0, nullptr,0, 1);
  gemm(0,1, h_bf,256,0, gate_w2,256,0, BQ_,256,256, gate_b2,2, gatebuf,nullptr,256,0, nullptr,0, nullptr,0, 1);
  combine_gate<<<BQ_,256,0,stream>>>(q, q_pos, alignedv, gatebuf, qx, qx_bf, qk_bf);

  // --- self attention (KV-split: 4 chunks of 64 over Lk=200) ---
  gemm(0,1, qk_bf,256,0, sa_in_w,256,0, BQ_,512,256, sa_in_b,0, nullptr,qkv_bf,768,0, nullptr,0, nullptr,0, 1);
  gemm(0,1, qx_bf,256,0, sa_in_w+512*256,256,0, BQ_,256,256, sa_in_b+512,0, nullptr,qkv_bf+512,768,0, nullptr,0, nullptr,0, 1);
  attn_kernel<<<dim3(4*NSPLIT,H_,B_),256,0,stream>>>(qkv_bf,768, qkv_bf,768,256,512,200,
      nullptr,nullptr, NSPLIT,64, opart,mlpart, ascale);
  attn_combine<<<BQ_,256,0,stream>>>(opart, mlpart, NSPLIT, attO_bf);
  gemm(0,1, attO_bf,256,0, sa_out_w,256,0, BQ_,256,256, sa_out_b,0, q2,nullptr,256,0, nullptr,0, nullptr,0, 1);
  add_ln<<<BQ_,256,0,stream>>>(qx, q2, n1_g, n1_b, q_pos, qx, qx_bf, qpos2_bf);

  // --- cross-memory sparsify (importance = max over Q of sim2, then top-1024) ---
  gemm(0,1, qx_bf,256,0, cross_wq,256,0, BQ_,256,256, nullptr,0, nullptr,qn_bf,256,0, nullptr,0, nullptr,0, 1);
  l2norm_rows<<<BQ_/4,256,0,stream>>>(qn_bf, BQ_);
  fill_u32<<<(B_*K_+255)/256,256,0,stream>>>(imp, 0u, B_*K_);
  if (fullws){
    gemm(1,1, memory,256,0, cross_wm,256,0, BK_,256,256, nullptr,0, nullptr,mn_bf,256,0, nullptr,0, nullptr,0, 1);
    l2norm_rows<<<BK_/4,256,0,stream>>>(mn_bf, BK_);
    gemm(0,0, qn_bf,256,(long)200*256, mn_bf,256,(long)K_*256, 200,K_,256,
         nullptr,0, nullptr,nullptr,0,0, imp,(long)K_, nullptr,0, B_);
  } else {
    for (int b=0;b<B_;b++){
      gemm(1,1, memory + (size_t)b*K_*256,256,0, cross_wm,256,0, K_,256,256,
           nullptr,0, nullptr,mn_bf,256,0, nullptr,0, nullptr,0, 1);
      l2norm_rows<<<K_/4,256,0,stream>>>(mn_bf, K_);
      gemm(0,0, qn_bf + (size_t)b*200*256,256,0, mn_bf,256,0, 200,K_,256,
           nullptr,0, nullptr,nullptr,0,0, imp + (size_t)b*K_,(long)K_, nullptr,0, 1);
    }
  }
  topk_kernel<<<B_,256,0,stream>>>(nullptr, imp, K_, CROSSK_, vals96 /*scratch*/, kidx);

  // --- cross attention (kvbuf aliases mn region; mn is dead now) ---
  gemm(1,1, memory,256,(long)K_*256, ca_in_w+256*256,256,0, CROSSK_,512,256,
       ca_in_b+256,0, nullptr,kvbuf,512,(long)CROSSK_*512, nullptr,0, kidx,(long)CROSSK_, B_);
  gemm(0,1, qpos2_bf,256,0, ca_in_w,256,0, BQ_,256,256, ca_in_b,0, nullptr,cq_bf,256,0, nullptr,0, nullptr,0, 1);
  attn_kernel<<<dim3(4*NSPLIT,H_,B_),256,0,stream>>>(cq_bf,256, kvbuf,512,0,256,CROSSK_,
      cbias, kidx, NSPLIT,256, opart,mlpart, ascale);
  attn_combine<<<BQ_,256,0,stream>>>(opart, mlpart, NSPLIT, attO_bf);
  gemm(0,1, attO_bf,256,0, ca_out_w,256,0, BQ_,256,256, ca_out_b,0, q2,nullptr,256,0, nullptr,0, nullptr,0, 1);
  add_ln<<<BQ_,256,0,stream>>>(qx, q2, n2_g, n2_b, nullptr, qx, qx_bf, nullptr);

  // --- FFN + final LN -> d_out (fp32) ---
  gemm(0,1, qx_bf,256,0, ffn_w1,256,0, BQ_,FF_,256, ffn_b1,1, nullptr,f1_bf,FF_,0, nullptr,0, nullptr,0, 1);
  gemm(0,1, f1_bf,FF_,0, ffn_w2,FF_,0, BQ_,256,FF_, ffn_b2,0, f2buf,nullptr,256,0, nullptr,0, nullptr,0, 1);
  add_ln<<<BQ_,256,0,stream>>>(qx, f2buf, n3_g, n3_b, nullptr, out, nullptr, nullptr);

  (void)in_sizes; (void)n_in; (void)out_size;
}

// Round 3
// 1113.205 us; speedup vs baseline: 1.1527x; 1.1527x over previous
//
#include <hip/hip_runtime.h>
#include <hip/hip_bf16.h>
#include <math.h>

// Problem constants
#define B_ 8
#define Q_ 200
#define K_ 16384
#define D_ 256
#define H_ 8
#define DH_ 32
#define ALIGNK_ 96
#define CROSSK_ 1024
#define FF_ 1024
#define BQ_ (B_*Q_)     // 1600
#define BK_ (B_*K_)     // 131072

typedef unsigned short u16;
typedef short bf16x8 __attribute__((ext_vector_type(8)));
typedef float f32x4 __attribute__((ext_vector_type(4)));

__device__ __forceinline__ float b2f(u16 u){ return __uint_as_float(((unsigned)u)<<16); }
__device__ __forceinline__ u16 f2b(float f){
  unsigned x = __float_as_uint(f);
  unsigned r = x + 0x7FFFu + ((x>>16)&1u);   // round-to-nearest-even
  return (u16)(r>>16);
}
__device__ __forceinline__ unsigned p2u(float lo, float hi){
  return (unsigned)f2b(lo) | ((unsigned)f2b(hi)<<16);
}
__device__ __forceinline__ uint4 pk8(float4 a, float4 b){
  return make_uint4(p2u(a.x,a.y), p2u(a.z,a.w), p2u(b.x,b.y), p2u(b.z,b.w));
}
// order-preserving float->uint key (larger float => larger key)
__device__ __forceinline__ unsigned fkey(float f){ unsigned b=__float_as_uint(f); return (b&0x80000000u)? ~b : (b|0x80000000u); }
__device__ __forceinline__ float funkey(unsigned k){ unsigned b=(k&0x80000000u)? (k^0x80000000u) : ~k; return __uint_as_float(b); }
__device__ __forceinline__ float gelu_f(float x){ return 0.5f*x*(1.0f+erff(x*0.70710678118654752f)); }
__device__ __forceinline__ float sigmoid_f(float x){ return 1.0f/(1.0f+__expf(-x)); }

// ---------------------------------------------------------------------------
// General NT GEMM:  C[m,n] = sum_k A[m,k]*B[n,k]  (fp32 acc). A/B each either
// fp32 (converted to bf16 in registers) or bf16. Tile 64x64, BK=64, 4 waves.
// Modes: optional fp32 bias[n], act (1=gelu,2=sigmoid), out fp32 or bf16,
//        per-column atomic-max (importance), optional A-row gather.
// ---------------------------------------------------------------------------
struct GArgs {
  const void* A; const void* B; const float* bias;
  float* Cf; u16* Cb; unsigned* amax;
  const int* gather;
  long lda, ldb, ldc;
  long sA, sB, sC, sAmax, sGather;
  int M, N, K, act;
};

template<int AF32, int BF32>
__global__ __launch_bounds__(256) void gemm_bt(GArgs g)
{
  const int tid = threadIdx.x;
  const int bz = blockIdx.z;
  const int m0 = blockIdx.y*64, n0 = blockIdx.x*64;
  const int lane = tid & 63, wave = tid >> 6;
  const int wr = wave >> 1, wc = wave & 1;
  __shared__ __align__(16) u16 As[64][72];
  __shared__ __align__(16) u16 Bs[64][72];
  f32x4 acc[2][2] = {};

  const int lrow = tid>>2;
  const int lk = (tid&3)*16;
  int ar = m0 + lrow; if (ar > g.M-1) ar = g.M-1;
  if (g.gather) ar = g.gather[(long)bz*g.sGather + ar];
  int br = n0 + lrow; if (br > g.N-1) br = g.N-1;
  long aoff = (long)bz*g.sA + (long)ar*g.lda + lk;
  long boff = (long)bz*g.sB + (long)br*g.ldb + lk;

  const int nk = g.K >> 6;
  for (int kt=0; kt<nk; ++kt){
    uint4 wa0, wa1, wb0, wb1;
    if (AF32){
      const float* p = (const float*)g.A + aoff;
      float4 f0 = *(const float4*)(p+0);
      float4 f1 = *(const float4*)(p+4);
      float4 f2v= *(const float4*)(p+8);
      float4 f3 = *(const float4*)(p+12);
      wa0 = pk8(f0,f1); wa1 = pk8(f2v,f3);
    } else {
      const u16* p = (const u16*)g.A + aoff;
      wa0 = *(const uint4*)p; wa1 = *(const uint4*)(p+8);
    }
    if (BF32){
      const float* p = (const float*)g.B + boff;
      float4 f0 = *(const float4*)(p+0);
      float4 f1 = *(const float4*)(p+4);
      float4 f2v= *(const float4*)(p+8);
      float4 f3 = *(const float4*)(p+12);
      wb0 = pk8(f0,f1); wb1 = pk8(f2v,f3);
    } else {
      const u16* p = (const u16*)g.B + boff;
      wb0 = *(const uint4*)p; wb1 = *(const uint4*)(p+8);
    }
    aoff += 64; boff += 64;
    __syncthreads();
    *(uint4*)&As[lrow][lk]   = wa0; *(uint4*)&As[lrow][lk+8] = wa1;
    *(uint4*)&Bs[lrow][lk]   = wb0; *(uint4*)&Bs[lrow][lk+8] = wb1;
    __syncthreads();
    #pragma unroll
    for (int kk=0; kk<2; ++kk){
      const int ko = kk*32 + (lane>>4)*8;
      bf16x8 af0 = *(const bf16x8*)&As[wr*32      + (lane&15)][ko];
      bf16x8 af1 = *(const bf16x8*)&As[wr*32 + 16 + (lane&15)][ko];
      bf16x8 bf0 = *(const bf16x8*)&Bs[wc*32      + (lane&15)][ko];
      bf16x8 bf1 = *(const bf16x8*)&Bs[wc*32 + 16 + (lane&15)][ko];
      acc[0][0] = __builtin_amdgcn_mfma_f32_16x16x32_bf16(af0, bf0, acc[0][0], 0,0,0);
      acc[0][1] = __builtin_amdgcn_mfma_f32_16x16x32_bf16(af0, bf1, acc[0][1], 0,0,0);
      acc[1][0] = __builtin_amdgcn_mfma_f32_16x16x32_bf16(af1, bf0, acc[1][0], 0,0,0);
      acc[1][1] = __builtin_amdgcn_mfma_f32_16x16x32_bf16(af1, bf1, acc[1][1], 0,0,0);
    }
  }

  if (g.amax){
    // per-column max over rows (M-clamp duplicates a valid row -> max unaffected)
    #pragma unroll
    for (int j=0;j<2;j++){
      float mx = -3.0e38f;
      #pragma unroll
      for (int i=0;i<2;i++)
        #pragma unroll
        for (int r=0;r<4;r++) mx = fmaxf(mx, acc[i][j][r]);
      mx = fmaxf(mx, __shfl_xor(mx, 16));
      mx = fmaxf(mx, __shfl_xor(mx, 32));
      if ((lane>>4)==0){
        int n = n0 + wc*32 + j*16 + (lane&15);
        if (n < g.N) atomicMax(&g.amax[(long)bz*g.sAmax + n], fkey(mx));
      }
    }
    return;
  }

  #pragma unroll
  for (int i=0;i<2;i++)
  #pragma unroll
  for (int j=0;j<2;j++)
  #pragma unroll
  for (int r=0;r<4;r++){
    int m = m0 + wr*32 + i*16 + (lane>>4)*4 + r;   // C row = quad*4+reg
    int n = n0 + wc*32 + j*16 + (lane&15);          // C col = lane&15
    if (m < g.M && n < g.N){
      float v = acc[i][j][r];
      if (g.bias) v += g.bias[n];
      if (g.act==1) v = gelu_f(v);
      else if (g.act==2) v = sigmoid_f(v);
      long ci = (long)bz*g.sC + (long)m*g.ldc + n;
      if (g.Cf) g.Cf[ci] = v; else g.Cb[ci] = f2b(v);
    }
  }
}

// ---------------------------------------------------------------------------
// In-place row l2-normalize (D=256, bf16), x /= max(||x||,1e-6). 4 rows/block.
// ---------------------------------------------------------------------------
__global__ __launch_bounds__(256) void l2norm_rows(u16* x, int rows)
{
  int row = blockIdx.x*4 + (threadIdx.x>>6);
  int lane = threadIdx.x & 63;
  if (row >= rows) return;
  u16* p = x + (long)row*256;
  float v[4]; float s = 0.f;
  #pragma unroll
  for (int i=0;i<4;i++){ v[i] = b2f(p[lane + i*64]); s += v[i]*v[i]; }
  #pragma unroll
  for (int off=32; off; off>>=1) s += __shfl_xor(s, off);
  float inv = 1.0f / fmaxf(sqrtf(s), 1e-6f);
  #pragma unroll
  for (int i=0;i<4;i++) p[lane + i*64] = f2b(v[i]*inv);
}

// ---------------------------------------------------------------------------
// Exact top-RANK of a 16384-long row. Bitwise rank-select on order-preserving
// keys + index tie-break (smallest indices first) == jax.lax.top_k's set.
// Early exit: if count(>= cand) == RANK at any prefix, {k >= cand} IS the
// top-RANK set (everything outside is strictly smaller) -> skip remaining
// bits AND the tie-break. Common case for distinct fp32 keys.
// Element mapping (vectorized load): e(j) = tid*4 + (j&3) + (j>>2)*1024.
// ---------------------------------------------------------------------------
__global__ __launch_bounds__(256) void topk_kernel(const float* inF, const unsigned* inK,
    long in_stride, int RANK, float* out_val, int* out_idx)
{
  __shared__ int red[2][4];
  __shared__ int redt[4];
  __shared__ int poss;
  int row = blockIdx.x, tid = threadIdx.x;
  unsigned kr[64];
  if (inF){
    const float4* p = (const float4*)(inF + (long)row*in_stride);
    #pragma unroll
    for (int jj=0;jj<16;jj++){
      float4 v = p[tid + jj*256];
      kr[jj*4+0]=fkey(v.x); kr[jj*4+1]=fkey(v.y); kr[jj*4+2]=fkey(v.z); kr[jj*4+3]=fkey(v.w);
    }
  } else {
    const uint4* p = (const uint4*)(inK + (long)row*in_stride);
    #pragma unroll
    for (int jj=0;jj<16;jj++){
      uint4 v = p[tid + jj*256];
      kr[jj*4+0]=v.x; kr[jj*4+1]=v.y; kr[jj*4+2]=v.z; kr[jj*4+3]=v.w;
    }
  }
  if (tid==0) poss = 0;

  unsigned u = 0; bool exact = false; int pp = 0;
  for (int bit=31; bit>=0; --bit){
    unsigned cand = u | (1u<<bit);
    int c = 0;
    #pragma unroll
    for (int j=0;j<64;j++) c += (kr[j] >= cand) ? 1 : 0;
    #pragma unroll
    for (int off=32; off; off>>=1) c += __shfl_down(c, off);
    if ((tid&63)==0) red[pp][tid>>6] = c;
    __syncthreads();
    c = red[pp][0]+red[pp][1]+red[pp][2]+red[pp][3];
    pp ^= 1;
    if (c >= RANK){
      u = cand;
      if (c == RANK){ exact = true; break; }   // uniform decision -> safe break
    }
  }

  int t = 0;
  if (!exact){
    int cgt = 0;
    #pragma unroll
    for (int j=0;j<64;j++) cgt += (kr[j] > u) ? 1 : 0;
    #pragma unroll
    for (int off=32; off; off>>=1) cgt += __shfl_down(cgt, off);
    __syncthreads();
    if ((tid&63)==0) redt[tid>>6] = cgt;
    __syncthreads();
    cgt = redt[0]+redt[1]+redt[2]+redt[3];
    int Req = RANK - cgt;   // >=1 always
    for (int bit=13; bit>=0; --bit){
      int cand = t | (1<<bit);
      int c = 0;
      #pragma unroll
      for (int j=0;j<64;j++){
        int e = (tid<<2) + (j&3) + ((j>>2)<<10);
        c += (kr[j]==u && e < cand) ? 1 : 0;
      }
      #pragma unroll
      for (int off=32; off; off>>=1) c += __shfl_down(c, off);
      __syncthreads();
      if ((tid&63)==0) redt[tid>>6] = c;
      __syncthreads();
      c = redt[0]+redt[1]+redt[2]+redt[3];
      if (c < Req) t = cand;
    }
  }
  __syncthreads();
  #pragma unroll
  for (int j=0;j<64;j++){
    int e = (tid<<2) + (j&3) + ((j>>2)<<10);
    unsigned kk = kr[j];
    bool win = exact ? (kk >= u) : (kk > u || (kk == u && e <= t));
    if (win){
      int p2 = atomicAdd(&poss, 1);
      out_val[(long)row*RANK + p2] = funkey(kk);
      out_idx[(long)row*RANK + p2] = e;
    }
  }
}

// ---------------------------------------------------------------------------
// aligned[row,:] = softmax(vals96) . memory[b, idx96, :]   (memory fp32)
// ---------------------------------------------------------------------------
__global__ __launch_bounds__(256) void align_combine(const float* vals, const int* idx,
    const float* memory, float* alignedv)
{
  __shared__ float w[96];
  __shared__ int id[96];
  __shared__ float reds[2];
  int row = blockIdx.x, tid = threadIdx.x;
  int b = row / 200;
  if (tid < 96){ w[tid] = vals[(long)row*96 + tid]; id[tid] = idx[(long)row*96 + tid]; }
  __syncthreads();
  if (tid < 64){
    float a = w[tid];
    float bb2 = (tid < 32) ? w[64+tid] : -3e38f;
    float m = fmaxf(a, bb2);
    #pragma unroll
    for (int off=32; off; off>>=1) m = fmaxf(m, __shfl_xor(m, off));
    if (tid==0) reds[0] = m;
  }
  __syncthreads();
  float m = reds[0];
  if (tid < 96) w[tid] = __expf(w[tid]-m);
  __syncthreads();
  if (tid < 64){
    float a = w[tid] + ((tid<32)? w[64+tid] : 0.f);
    #pragma unroll
    for (int off=32; off; off>>=1) a += __shfl_xor(a, off);
    if (tid==0) reds[1] = a;
  }
  __syncthreads();
  float invs = 1.0f/reds[1];
  float acc = 0.f;
  const float* mb = memory + (long)b*K_*D_;
  for (int k=0;k<96;k++) acc += w[k] * mb[(long)id[k]*D_ + tid];
  alignedv[(long)row*256 + tid] = acc*invs;
}

__global__ void make_cat(const float* q, const float* alignedv, u16* cat)
{
  int row = blockIdx.x, tid = threadIdx.x;
  long i = (long)row*256 + tid;
  cat[(long)row*512 + tid]       = f2b(q[i]);
  cat[(long)row*512 + 256 + tid] = f2b(alignedv[i]);
}

__global__ void combine_gate(const float* q, const float* q_pos, const float* alignedv,
    const float* gate, float* qx, u16* qx_b, u16* qk_b)
{
  int row = blockIdx.x, tid = threadIdx.x;
  long i = (long)row*256 + tid;
  float v = q[i] + gate[i]*alignedv[i];
  qx[i] = v;
  qx_b[i] = f2b(v);
  qk_b[i] = f2b(v + q_pos[i]);
}

// ---------------------------------------------------------------------------
// t = x + y; LN over D=256 (biased var, eps 1e-5). Optional outputs.
// fminf/fmaxf launder NaN (return the non-NaN operand) -> finite diagnostics.
// ---------------------------------------------------------------------------
__global__ __launch_bounds__(256) void add_ln(const float* x, const float* y,
    const float* g, const float* bb, const float* q_pos,
    float* out_f, u16* out_b, u16* out_pos_b)
{
  __shared__ float red[8];
  int row = blockIdx.x, tid = threadIdx.x;
  long i = (long)row*256 + tid;
  float t = fminf(fmaxf(x[i] + y[i], -1e6f), 1e6f);
  float s1 = t, s2 = t*t;
  #pragma unroll
  for (int off=32; off; off>>=1){ s1 += __shfl_down(s1,off); s2 += __shfl_down(s2,off); }
  if ((tid&63)==0){ red[(tid>>6)*2] = s1; red[(tid>>6)*2+1] = s2; }
  __syncthreads();
  s1 = red[0]+red[2]+red[4]+red[6];
  s2 = red[1]+red[3]+red[5]+red[7];
  float mu = s1 * (1.0f/256.0f);
  float var = fmaxf(s2 * (1.0f/256.0f) - mu*mu, 0.f);
  float rstd = rsqrtf(var + 1e-5f);
  float v = (t-mu)*rstd*g[tid] + bb[tid];
  if (out_f) out_f[i] = v;
  if (out_b) out_b[i] = f2b(v);
  if (out_pos_b) out_pos_b[i] = f2b(v + q_pos[i]);
}

__global__ void fill_u32(unsigned* p, unsigned val, int n)
{ int i = blockIdx.x*256 + threadIdx.x; if (i<n) p[i] = val; }

// ---------------------------------------------------------------------------
// Pre-gather cross-attn bias into dense biasT[b][j][q] (j = position in kidx).
// One pass of 1.6M scattered reads instead of 8x (per-head) inside attn.
// Writes coalesced over q.
// ---------------------------------------------------------------------------
__global__ __launch_bounds__(256) void bias_gather(const float* cbias, const int* kidx,
    float* biasT)
{
  int b = blockIdx.y;
  int j = blockIdx.x*8 + (threadIdx.x>>5);
  int q = threadIdx.x & 31;
  int kid = kidx[b*CROSSK_ + j];
  const float* src = cbias + (long)b*Q_*K_ + kid;
  float* dst = biasT + ((long)b*CROSSK_ + j)*200;
  for (int qq=q; qq<200; qq+=32) dst[qq] = src[(long)qq*K_];
}

// ---------------------------------------------------------------------------
// Fused MHA, flash-style with KV-split (flash-decoding). One block per
// (b, h, 64-q-tile, kv-split). Scores kept in registers; each thread
// accumulates all 32 dims for its q-row quadrant, quad-reduced via shfl.
// Bias (cross) read from dense pre-gathered biasT[b][j][q].
// Partial (o, m, l) written fp32; combined separately.
// ---------------------------------------------------------------------------
__global__ __launch_bounds__(256) void attn_kernel(
    const u16* Qb, int q_stride,
    const u16* KVb, int kv_stride, int k_off, int v_off, int Lk,
    const float* biasT,
    int nsplit, int chunk,
    float* opart, float* mlpart, float scale)
{
  __shared__ float Ks[64][36];
  __shared__ float Vs[64][36];
  const int b = blockIdx.z, h = blockIdx.y;
  const int split = blockIdx.x % nsplit;
  const int q0 = (blockIdx.x / nsplit) * 64;
  const int tid = threadIdx.x;
  const int cg = tid & 3, r = tid >> 2;
  const int kbeg = split*chunk;
  int kend = kbeg + chunk; if (kend > Lk) kend = Lk;

  int qr = q0 + r; if (qr > 199) qr = 199;
  float qreg[32];
  {
    const u16* qp = Qb + (long)(b*200+qr)*q_stride + h*32;
    #pragma unroll
    for (int w=0; w<4; w++){
      uint4 u = *(const uint4*)(qp + w*8);
      qreg[w*8+0]=b2f((u16)(u.x&0xffffu))*scale; qreg[w*8+1]=b2f((u16)(u.x>>16))*scale;
      qreg[w*8+2]=b2f((u16)(u.y&0xffffu))*scale; qreg[w*8+3]=b2f((u16)(u.y>>16))*scale;
      qreg[w*8+4]=b2f((u16)(u.z&0xffffu))*scale; qreg[w*8+5]=b2f((u16)(u.z>>16))*scale;
      qreg[w*8+6]=b2f((u16)(u.w&0xffffu))*scale; qreg[w*8+7]=b2f((u16)(u.w>>16))*scale;
    }
  }
  // dense bias base for this (b, q-row): biasT[b][j][qglob], walk j
  const float* bT = biasT ? biasT + ((long)b*CROSSK_)*200 + qr : nullptr;

  float o32[32];
  #pragma unroll
  for (int i=0;i<32;i++) o32[i]=0.f;
  float mrun = -3e38f, lrun = 0.f;

  const int srow = tid>>2, sc8 = (tid&3)*8;   // staging: 1 uint4 per matrix
  for (int j0=kbeg; j0<kend; j0+=64){
    // issue global loads early (overlap with prior tile's LDS reads)
    int kr = j0 + srow; if (kr > kend-1) kr = kend-1;
    const long base = (long)(b*Lk + kr)*kv_stride;
    uint4 ku = *(const uint4*)(KVb + base + k_off + sc8);
    uint4 vu = *(const uint4*)(KVb + base + v_off + sc8);
    __syncthreads();   // prior tile fully consumed
    {
      float4 f0, f1;
      f0.x=b2f((u16)(ku.x&0xffffu)); f0.y=b2f((u16)(ku.x>>16)); f0.z=b2f((u16)(ku.y&0xffffu)); f0.w=b2f((u16)(ku.y>>16));
      f1.x=b2f((u16)(ku.z&0xffffu)); f1.y=b2f((u16)(ku.z>>16)); f1.z=b2f((u16)(ku.w&0xffffu)); f1.w=b2f((u16)(ku.w>>16));
      *(float4*)&Ks[srow][sc8] = f0; *(float4*)&Ks[srow][sc8+4] = f1;
      f0.x=b2f((u16)(vu.x&0xffffu)); f0.y=b2f((u16)(vu.x>>16)); f0.z=b2f((u16)(vu.y&0xffffu)); f0.w=b2f((u16)(vu.y>>16));
      f1.x=b2f((u16)(vu.z&0xffffu)); f1.y=b2f((u16)(vu.z>>16)); f1.z=b2f((u16)(vu.w&0xffffu)); f1.w=b2f((u16)(vu.w>>16));
      *(float4*)&Vs[srow][sc8] = f0; *(float4*)&Vs[srow][sc8+4] = f1;
    }
    __syncthreads();

    float sv[16];
    float mloc = -3e38f;
    #pragma unroll
    for (int jj=0;jj<16;jj++){
      const int c = cg + jj*4;
      const float4* kp = (const float4*)&Ks[c][0];
      float a = 0.f;
      #pragma unroll
      for (int dq=0;dq<8;dq++){
        float4 kv = kp[dq];
        a += qreg[dq*4+0]*kv.x + qreg[dq*4+1]*kv.y + qreg[dq*4+2]*kv.z + qreg[dq*4+3]*kv.w;
      }
      if (biasT) a += bT[(long)(j0 + c)*200];
      if (j0 + c >= kend) a = -3e38f;
      sv[jj] = a; mloc = fmaxf(mloc, a);
    }
    mloc = fmaxf(mloc, __shfl_xor(mloc,1));
    mloc = fmaxf(mloc, __shfl_xor(mloc,2));
    const float mnew = fmaxf(mrun, mloc);
    const float alpha = __expf(mrun - mnew);
    float lloc = 0.f;
    #pragma unroll
    for (int jj=0;jj<16;jj++){
      float p = (j0 + cg + jj*4 >= kend) ? 0.f : __expf(sv[jj]-mnew);
      sv[jj] = p; lloc += p;
    }
    lloc += __shfl_xor(lloc,1);
    lloc += __shfl_xor(lloc,2);
    lrun = lrun*alpha + lloc;
    #pragma unroll
    for (int i=0;i<32;i++) o32[i] *= alpha;
    #pragma unroll
    for (int jj=0;jj<16;jj++){
      const int c = cg + jj*4;
      const float p = sv[jj];
      const float4* vp = (const float4*)&Vs[c][0];
      #pragma unroll
      for (int dq=0;dq<8;dq++){
        float4 v = vp[dq];
        o32[dq*4+0] += p*v.x; o32[dq*4+1] += p*v.y; o32[dq*4+2] += p*v.z; o32[dq*4+3] += p*v.w;
      }
    }
    mrun = mnew;
  }

  // reduce across the quad (lanes xor 1, 2) -> full sums on all 4 lanes
  #pragma unroll
  for (int d=0;d<32;d++){
    float v = o32[d];
    v += __shfl_xor(v,1);
    v += __shfl_xor(v,2);
    o32[d] = v;
  }
  if (q0 + r < 200){
    const long pbase = (((long)(b*H_+h)*nsplit + split)*200) + (q0 + r);
    float* op = opart + pbase*32;
    #pragma unroll
    for (int i=0;i<8;i++) op[cg*8+i] = o32[cg*8+i];
    if (cg==0){ mlpart[pbase*2] = mrun; mlpart[pbase*2+1] = lrun; }
  }
}

// Combine KV-split partials: out = sum_s o_s*exp(m_s-M) / sum_s l_s*exp(m_s-M)
__global__ __launch_bounds__(256) void attn_combine(const float* opart, const float* mlpart,
    int nsplit, u16* outp)
{
  int row = blockIdx.x;                 // 0..BQ_-1
  int b = row/200, qi = row%200;
  int tid = threadIdx.x;
  int h = tid>>5, d = tid&31;
  const long base = ((long)(b*H_+h)*nsplit)*200 + qi;   // + s*200 per split
  float M = -3e38f;
  for (int s=0;s<nsplit;s++) M = fmaxf(M, mlpart[(base + (long)s*200)*2]);
  float L = 0.f, acc = 0.f;
  for (int s=0;s<nsplit;s++){
    const long ix = base + (long)s*200;
    float w = __expf(mlpart[ix*2] - M);
    L   += mlpart[ix*2+1]*w;
    acc += opart[ix*32 + d]*w;
  }
  outp[(long)row*256 + h*32 + d] = f2b(acc / fmaxf(L, 1e-30f));
}

// ---------------------------------------------------------------------------
extern "C" void kernel_launch(void* const* d_in, const int* in_sizes, int n_in,
                              void* d_out, int out_size, void* d_ws, size_t ws_size,
                              hipStream_t stream)
{
  const float* q        = (const float*)d_in[0];
  const float* q_pos    = (const float*)d_in[1];
  const float* memory   = (const float*)d_in[2];
  const float* cbias    = (const float*)d_in[3];
  const float* align_wq = (const float*)d_in[4];
  const float* align_wm = (const float*)d_in[5];
  const float* gate_w1  = (const float*)d_in[6];
  const float* gate_b1  = (const float*)d_in[7];
  const float* gate_w2  = (const float*)d_in[8];
  const float* gate_b2  = (const float*)d_in[9];
  const float* cross_wq = (const float*)d_in[10];
  const float* cross_wm = (const float*)d_in[11];
  const float* sa_in_w  = (const float*)d_in[12];
  const float* sa_in_b  = (const float*)d_in[13];
  const float* sa_out_w = (const float*)d_in[14];
  const float* sa_out_b = (const float*)d_in[15];
  const float* ca_in_w  = (const float*)d_in[16];
  const float* ca_in_b  = (const float*)d_in[17];
  const float* ca_out_w = (const float*)d_in[18];
  const float* ca_out_b = (const float*)d_in[19];
  const float* ffn_w1   = (const float*)d_in[20];
  const float* ffn_b1   = (const float*)d_in[21];
  const float* ffn_w2   = (const float*)d_in[22];
  const float* ffn_b2   = (const float*)d_in[23];
  const float* n1_g = (const float*)d_in[24];
  const float* n1_b = (const float*)d_in[25];
  const float* n2_g = (const float*)d_in[26];
  const float* n2_b = (const float*)d_in[27];
  const float* n3_g = (const float*)d_in[28];
  const float* n3_b = (const float*)d_in[29];
  float* out = (float*)d_out;   // reference output dtype is fp32

  // ---- workspace layout, fitted to ws_size (deterministic per call) ----
  char* wsb = (char*)d_ws;
  size_t off = 0;
  auto alloc = [&](size_t bytes)->char*{
    char* p = wsb + off; off = (off + bytes + 255) & ~(size_t)255; return p;
  };
  const int NSPLIT = 4;   // KV splits for both attentions
  // small fixed buffers (~36 MB)
  u16*    qn_bf   = (u16*)   alloc((size_t)BQ_*D_*2);
  float*  vals96  = (float*) alloc((size_t)BQ_*96*4);
  int*    idx96   = (int*)   alloc((size_t)BQ_*96*4);
  float*  alignedv= (float*) alloc((size_t)BQ_*D_*4);
  u16*    cat_bf  = (u16*)   alloc((size_t)BQ_*512*2);
  u16*    h_bf    = (u16*)   alloc((size_t)BQ_*D_*2);
  float*  gatebuf = (float*) alloc((size_t)BQ_*D_*4);
  float*  qx      = (float*) alloc((size_t)BQ_*D_*4);
  u16*    qx_bf   = (u16*)   alloc((size_t)BQ_*D_*2);
  u16*    qk_bf   = (u16*)   alloc((size_t)BQ_*D_*2);
  u16*    qpos2_bf= (u16*)   alloc((size_t)BQ_*D_*2);
  u16*    qkv_bf  = (u16*)   alloc((size_t)BQ_*768*2);
  u16*    attO_bf = (u16*)   alloc((size_t)BQ_*D_*2);
  float*  q2      = (float*) alloc((size_t)BQ_*D_*4);
  unsigned* imp   = (unsigned*)alloc((size_t)B_*K_*4);
  int*    kidx    = (int*)   alloc((size_t)B_*CROSSK_*4);
  u16*    cq_bf   = (u16*)   alloc((size_t)BQ_*D_*2);
  u16*    f1_bf   = (u16*)   alloc((size_t)BQ_*FF_*2);
  float*  f2buf   = (float*) alloc((size_t)BQ_*D_*4);
  float*  opart   = (float*) alloc((size_t)B_*H_*NSPLIT*200*32*4);  // 6.6 MB
  float*  mlpart  = (float*) alloc((size_t)B_*H_*NSPLIT*200*2*4);   // 0.4 MB
  float*  biasT   = (float*) alloc((size_t)B_*CROSSK_*200*4);       // 6.6 MB

  // big buffers: mn (>= kvbuf size, kvbuf aliases it) and simbuf
  const size_t kv_bytes   = (size_t)B_*CROSSK_*512*2;        // 8.4 MB
  const size_t mn_full    = (size_t)BK_*D_*2;                // 67 MB
  const size_t mn_small   = (size_t)K_*D_*2;                 // 8.4 MB
  const size_t sim_full   = (size_t)BQ_*K_*4;                // 105 MB
  size_t remain = (ws_size > off) ? ws_size - off : 0;
  bool fullws = remain >= mn_full + sim_full + (1u<<20);
  size_t mn_bytes = fullws ? mn_full : (mn_small > kv_bytes ? mn_small : kv_bytes);
  int simRows;                      // rows of sim materialized at once
  if (fullws) simRows = BQ_;
  else {
    size_t left = (remain > mn_bytes + (1u<<18)) ? remain - mn_bytes - (1u<<18) : 0;
    long r = (long)(left / ((size_t)K_*4));
    simRows = (int)(r < 8 ? 8 : (r > Q_ ? Q_ : r));
  }
  u16*   mn_bf  = (u16*)  alloc(mn_bytes);
  u16*   kvbuf  = (u16*)  mn_bf;     // alias: mn dead before kvbuf is written
  float* simbuf = (float*)alloc((size_t)simRows*K_*4);

  auto gemm = [&](int af32, int bf32,
                  const void* A, long lda, long sA,
                  const void* Bm, long ldb, long sB,
                  int M, int N, int Kd,
                  const float* bias, int act,
                  float* Cf, u16* Cb, long ldc, long sC,
                  unsigned* amax, long sAmax,
                  const int* gather, long sGather, int Z){
    GArgs ga;
    ga.A=A; ga.B=Bm; ga.bias=bias; ga.Cf=Cf; ga.Cb=Cb; ga.amax=amax; ga.gather=gather;
    ga.lda=lda; ga.ldb=ldb; ga.ldc=ldc; ga.sA=sA; ga.sB=sB; ga.sC=sC;
    ga.sAmax=sAmax; ga.sGather=sGather;
    ga.M=M; ga.N=N; ga.K=Kd; ga.act=act;
    dim3 grid(N/64, (M+63)/64, Z);
    if (af32 && bf32)      gemm_bt<1,1><<<grid, 256, 0, stream>>>(ga);
    else if (af32)         gemm_bt<1,0><<<grid, 256, 0, stream>>>(ga);
    else if (bf32)         gemm_bt<0,1><<<grid, 256, 0, stream>>>(ga);
    else                   gemm_bt<0,0><<<grid, 256, 0, stream>>>(ga);
  };
  const float ascale = 0.17677669529663687f;  // 1/sqrt(32)

  // --- align: projections + l2norm + sim + top-96 ---
  gemm(1,1, q,256,0, align_wq,256,0, BQ_,256,256, nullptr,0, nullptr,qn_bf,256,0, nullptr,0, nullptr,0, 1);
  l2norm_rows<<<BQ_/4,256,0,stream>>>(qn_bf, BQ_);
  if (fullws){
    gemm(1,1, memory,256,0, align_wm,256,0, BK_,256,256, nullptr,0, nullptr,mn_bf,256,0, nullptr,0, nullptr,0, 1);
    l2norm_rows<<<BK_/4,256,0,stream>>>(mn_bf, BK_);
    gemm(0,0, qn_bf,256,(long)200*256, mn_bf,256,(long)K_*256, 200,K_,256,
         nullptr,0, simbuf,nullptr,K_,(long)200*K_, nullptr,0, nullptr,0, B_);
    topk_kernel<<<BQ_,256,0,stream>>>(simbuf, nullptr, K_, 96, vals96, idx96);
  } else {
    for (int b=0;b<B_;b++){
      gemm(1,1, memory + (size_t)b*K_*256,256,0, align_wm,256,0, K_,256,256,
           nullptr,0, nullptr,mn_bf,256,0, nullptr,0, nullptr,0, 1);
      l2norm_rows<<<K_/4,256,0,stream>>>(mn_bf, K_);
      for (int q0=0; q0<Q_; q0+=simRows){
        int rows = (Q_ - q0 < simRows) ? (Q_ - q0) : simRows;
        gemm(0,0, qn_bf + ((size_t)b*200+q0)*256,256,0, mn_bf,256,0, rows,K_,256,
             nullptr,0, simbuf,nullptr,K_,0, nullptr,0, nullptr,0, 1);
        topk_kernel<<<rows,256,0,stream>>>(simbuf, nullptr, K_, 96,
             vals96 + ((size_t)b*200+q0)*96, idx96 + ((size_t)b*200+q0)*96);
      }
    }
  }
  align_combine<<<BQ_,256,0,stream>>>(vals96, idx96, memory, alignedv);

  // --- gate MLP ---
  make_cat<<<BQ_,256,0,stream>>>(q, alignedv, cat_bf);
  gemm(0,1, cat_bf,512,0, gate_w1,512,0, BQ_,256,512, gate_b1,1, nullptr,h_bf,256,0, nullptr,0, nullptr,0, 1);
  gemm(0,1, h_bf,256,0, gate_w2,256,0, BQ_,256,256, gate_b2,2, gatebuf,nullptr,256,0, nullptr,0, nullptr,0, 1);
  combine_gate<<<BQ_,256,0,stream>>>(q, q_pos, alignedv, gatebuf, qx, qx_bf, qk_bf);

  // --- self attention (KV-split: 4 chunks of 64 over Lk=200) ---
  gemm(0,1, qk_bf,256,0, sa_in_w,256,0, BQ_,512,256, sa_in_b,0, nullptr,qkv_bf,768,0, nullptr,0, nullptr,0, 1);
  gemm(0,1, qx_bf,256,0, sa_in_w+512*256,256,0, BQ_,256,256, sa_in_b+512,0, nullptr,qkv_bf+512,768,0, nullptr,0, nullptr,0, 1);
  attn_kernel<<<dim3(4*NSPLIT,H_,B_),256,0,stream>>>(qkv_bf,768, qkv_bf,768,256,512,200,
      nullptr, NSPLIT,64, opart,mlpart, ascale);
  attn_combine<<<BQ_,256,0,stream>>>(opart, mlpart, NSPLIT, attO_bf);
  gemm(0,1, attO_bf,256,0, sa_out_w,256,0, BQ_,256,256, sa_out_b,0, q2,nullptr,256,0, nullptr,0, nullptr,0, 1);
  add_ln<<<BQ_,256,0,stream>>>(qx, q2, n1_g, n1_b, q_pos, qx, qx_bf, qpos2_bf);

  // --- cross-memory sparsify (importance = max over Q of sim2, then top-1024) ---
  gemm(0,1, qx_bf,256,0, cross_wq,256,0, BQ_,256,256, nullptr,0, nullptr,qn_bf,256,0, nullptr,0, nullptr,0, 1);
  l2norm_rows<<<BQ_/4,256,0,stream>>>(qn_bf, BQ_);
  fill_u32<<<(B_*K_+255)/256,256,0,stream>>>(imp, 0u, B_*K_);
  if (fullws){
    gemm(1,1, memory,256,0, cross_wm,256,0, BK_,256,256, nullptr,0, nullptr,mn_bf,256,0, nullptr,0, nullptr,0, 1);
    l2norm_rows<<<BK_/4,256,0,stream>>>(mn_bf, BK_);
    gemm(0,0, qn_bf,256,(long)200*256, mn_bf,256,(long)K_*256, 200,K_,256,
         nullptr,0, nullptr,nullptr,0,0, imp,(long)K_, nullptr,0, B_);
  } else {
    for (int b=0;b<B_;b++){
      gemm(1,1, memory + (size_t)b*K_*256,256,0, cross_wm,256,0, K_,256,256,
           nullptr,0, nullptr,mn_bf,256,0, nullptr,0, nullptr,0, 1);
      l2norm_rows<<<K_/4,256,0,stream>>>(mn_bf, K_);
      gemm(0,0, qn_bf + (size_t)b*200*256,256,0, mn_bf,256,0, 200,K_,256,
           nullptr,0, nullptr,nullptr,0,0, imp + (size_t)b*K_,(long)K_, nullptr,0, 1);
    }
  }
  topk_kernel<<<B_,256,0,stream>>>(nullptr, imp, K_, CROSSK_, vals96 /*scratch*/, kidx);

  // --- cross attention (kvbuf aliases mn region; mn is dead now) ---
  bias_gather<<<dim3(CROSSK_/8, B_),256,0,stream>>>(cbias, kidx, biasT);
  gemm(1,1, memory,256,(long)K_*256, ca_in_w+256*256,256,0, CROSSK_,512,256,
       ca_in_b+256,0, nullptr,kvbuf,512,(long)CROSSK_*512, nullptr,0, kidx,(long)CROSSK_, B_);
  gemm(0,1, qpos2_bf,256,0, ca_in_w,256,0, BQ_,256,256, ca_in_b,0, nullptr,cq_bf,256,0, nullptr,0, nullptr,0, 1);
  attn_kernel<<<dim3(4*NSPLIT,H_,B_),256,0,stream>>>(cq_bf,256, kvbuf,512,0,256,CROSSK_,
      biasT, NSPLIT,256, opart,mlpart, ascale);
  attn_combine<<<BQ_,256,0,stream>>>(opart, mlpart, NSPLIT, attO_bf);
  gemm(0,1, attO_bf,256,0, ca_out_w,256,0, BQ_,256,256, ca_out_b,0, q2,nullptr,256,0, nullptr,0, nullptr,0, 1);
  add_ln<<<BQ_,256,0,stream>>>(qx, q2, n2_g, n2_b, nullptr, qx, qx_bf, nullptr);

  // --- FFN + final LN -> d_out (fp32) ---
  gemm(0,1, qx_bf,256,0, ffn_w1,256,0, BQ_,FF_,256, ffn_b1,1, nullptr,f1_bf,FF_,0, nullptr,0, nullptr,0, 1);
  gemm(0,1, f1_bf,FF_,0, ffn_w2,FF_,0, BQ_,256,FF_, ffn_b2,0, f2buf,nullptr,256,0, nullptr,0, nullptr,0, 1);
  add_ln<<<BQ_,256,0,stream>>>(qx, f2buf, n3_g, n3_b, nullptr, out, nullptr, nullptr);

  (void)in_sizes; (void)n_in; (void)out_size;
}

// Round 4
// 994.290 us; speedup vs baseline: 1.2906x; 1.1196x over previous
//
#include <hip/hip_runtime.h>
#include <hip/hip_bf16.h>
#include <math.h>

// Problem constants
#define B_ 8
#define Q_ 200
#define K_ 16384
#define D_ 256
#define H_ 8
#define DH_ 32
#define ALIGNK_ 96
#define CROSSK_ 1024
#define FF_ 1024
#define BQ_ (B_*Q_)     // 1600
#define BK_ (B_*K_)     // 131072

typedef unsigned short u16;
typedef short bf16x8 __attribute__((ext_vector_type(8)));
typedef float f32x4 __attribute__((ext_vector_type(4)));

__device__ __forceinline__ float b2f(u16 u){ return __uint_as_float(((unsigned)u)<<16); }
__device__ __forceinline__ u16 f2b(float f){
  unsigned x = __float_as_uint(f);
  unsigned r = x + 0x7FFFu + ((x>>16)&1u);   // round-to-nearest-even
  return (u16)(r>>16);
}
__device__ __forceinline__ unsigned p2u(float lo, float hi){
  return (unsigned)f2b(lo) | ((unsigned)f2b(hi)<<16);
}
__device__ __forceinline__ uint4 pk8(float4 a, float4 b){
  return make_uint4(p2u(a.x,a.y), p2u(a.z,a.w), p2u(b.x,b.y), p2u(b.z,b.w));
}
// order-preserving float->uint key (larger float => larger key)
__device__ __forceinline__ unsigned fkey(float f){ unsigned b=__float_as_uint(f); return (b&0x80000000u)? ~b : (b|0x80000000u); }
__device__ __forceinline__ float funkey(unsigned k){ unsigned b=(k&0x80000000u)? (k^0x80000000u) : ~k; return __uint_as_float(b); }
__device__ __forceinline__ float gelu_f(float x){ return 0.5f*x*(1.0f+erff(x*0.70710678118654752f)); }
__device__ __forceinline__ float sigmoid_f(float x){ return 1.0f/(1.0f+__expf(-x)); }

// ---------------------------------------------------------------------------
// General NT GEMM:  C[m,n] = sum_k A[m,k]*B[n,k]  (fp32 acc). A/B each either
// fp32 (converted to bf16 in registers) or bf16. Tile 64x64, BK=64, 4 waves.
// Modes: optional fp32 bias[n], act (1=gelu,2=sigmoid), out fp32 or bf16,
//        per-column atomic-max (importance), optional A-row gather.
// ---------------------------------------------------------------------------
struct GArgs {
  const void* A; const void* B; const float* bias;
  float* Cf; u16* Cb; unsigned* amax;
  const int* gather;
  long lda, ldb, ldc;
  long sA, sB, sC, sAmax, sGather;
  int M, N, K, act;
};

template<int AF32, int BF32>
__global__ __launch_bounds__(256) void gemm_bt(GArgs g)
{
  const int tid = threadIdx.x;
  const int bz = blockIdx.z;
  const int m0 = blockIdx.y*64, n0 = blockIdx.x*64;
  const int lane = tid & 63, wave = tid >> 6;
  const int wr = wave >> 1, wc = wave & 1;
  __shared__ __align__(16) u16 As[64][72];
  __shared__ __align__(16) u16 Bs[64][72];
  f32x4 acc[2][2] = {};

  const int lrow = tid>>2;
  const int lk = (tid&3)*16;
  int ar = m0 + lrow; if (ar > g.M-1) ar = g.M-1;
  if (g.gather) ar = g.gather[(long)bz*g.sGather + ar];
  int br = n0 + lrow; if (br > g.N-1) br = g.N-1;
  long aoff = (long)bz*g.sA + (long)ar*g.lda + lk;
  long boff = (long)bz*g.sB + (long)br*g.ldb + lk;

  const int nk = g.K >> 6;
  for (int kt=0; kt<nk; ++kt){
    uint4 wa0, wa1, wb0, wb1;
    if (AF32){
      const float* p = (const float*)g.A + aoff;
      float4 f0 = *(const float4*)(p+0);
      float4 f1 = *(const float4*)(p+4);
      float4 f2v= *(const float4*)(p+8);
      float4 f3 = *(const float4*)(p+12);
      wa0 = pk8(f0,f1); wa1 = pk8(f2v,f3);
    } else {
      const u16* p = (const u16*)g.A + aoff;
      wa0 = *(const uint4*)p; wa1 = *(const uint4*)(p+8);
    }
    if (BF32){
      const float* p = (const float*)g.B + boff;
      float4 f0 = *(const float4*)(p+0);
      float4 f1 = *(const float4*)(p+4);
      float4 f2v= *(const float4*)(p+8);
      float4 f3 = *(const float4*)(p+12);
      wb0 = pk8(f0,f1); wb1 = pk8(f2v,f3);
    } else {
      const u16* p = (const u16*)g.B + boff;
      wb0 = *(const uint4*)p; wb1 = *(const uint4*)(p+8);
    }
    aoff += 64; boff += 64;
    __syncthreads();
    *(uint4*)&As[lrow][lk]   = wa0; *(uint4*)&As[lrow][lk+8] = wa1;
    *(uint4*)&Bs[lrow][lk]   = wb0; *(uint4*)&Bs[lrow][lk+8] = wb1;
    __syncthreads();
    #pragma unroll
    for (int kk=0; kk<2; ++kk){
      const int ko = kk*32 + (lane>>4)*8;
      bf16x8 af0 = *(const bf16x8*)&As[wr*32      + (lane&15)][ko];
      bf16x8 af1 = *(const bf16x8*)&As[wr*32 + 16 + (lane&15)][ko];
      bf16x8 bf0 = *(const bf16x8*)&Bs[wc*32      + (lane&15)][ko];
      bf16x8 bf1 = *(const bf16x8*)&Bs[wc*32 + 16 + (lane&15)][ko];
      acc[0][0] = __builtin_amdgcn_mfma_f32_16x16x32_bf16(af0, bf0, acc[0][0], 0,0,0);
      acc[0][1] = __builtin_amdgcn_mfma_f32_16x16x32_bf16(af0, bf1, acc[0][1], 0,0,0);
      acc[1][0] = __builtin_amdgcn_mfma_f32_16x16x32_bf16(af1, bf0, acc[1][0], 0,0,0);
      acc[1][1] = __builtin_amdgcn_mfma_f32_16x16x32_bf16(af1, bf1, acc[1][1], 0,0,0);
    }
  }

  if (g.amax){
    // per-column max over rows (M-clamp duplicates a valid row -> max unaffected)
    #pragma unroll
    for (int j=0;j<2;j++){
      float mx = -3.0e38f;
      #pragma unroll
      for (int i=0;i<2;i++)
        #pragma unroll
        for (int r=0;r<4;r++) mx = fmaxf(mx, acc[i][j][r]);
      mx = fmaxf(mx, __shfl_xor(mx, 16));
      mx = fmaxf(mx, __shfl_xor(mx, 32));
      if ((lane>>4)==0){
        int n = n0 + wc*32 + j*16 + (lane&15);
        if (n < g.N) atomicMax(&g.amax[(long)bz*g.sAmax + n], fkey(mx));
      }
    }
    return;
  }

  #pragma unroll
  for (int i=0;i<2;i++)
  #pragma unroll
  for (int j=0;j<2;j++)
  #pragma unroll
  for (int r=0;r<4;r++){
    int m = m0 + wr*32 + i*16 + (lane>>4)*4 + r;   // C row = quad*4+reg
    int n = n0 + wc*32 + j*16 + (lane&15);          // C col = lane&15
    if (m < g.M && n < g.N){
      float v = acc[i][j][r];
      if (g.bias) v += g.bias[n];
      if (g.act==1) v = gelu_f(v);
      else if (g.act==2) v = sigmoid_f(v);
      long ci = (long)bz*g.sC + (long)m*g.ldc + n;
      if (g.Cf) g.Cf[ci] = v; else g.Cb[ci] = f2b(v);
    }
  }
}

// ---------------------------------------------------------------------------
// Fused projection + row-L2-normalize:
//   out[m,:] = l2norm( A[m,:] @ W.T )   A: [R][256] fp32 or bf16, W: [256][256] fp32
// Tile: 64 rows x ALL 256 cols, K chunked by 64. Each wave owns 16 rows x 256
// cols, so the row norm is computed in-registers (xor-shuffle over the 16
// column-lanes) and normalized bf16 is written directly. A fetched ONCE.
// LDS: As 9.2KB + Bs 36.9KB.
// ---------------------------------------------------------------------------
template<int AF32>
__global__ __launch_bounds__(256) void proj_l2norm(
    const void* Ain, long lda, const float* W, u16* outp, int R)
{
  __shared__ __align__(16) u16 As[64][72];
  __shared__ __align__(16) u16 Bs[256][72];
  const int tid = threadIdx.x;
  const int m0 = blockIdx.x*64;
  const int lane = tid & 63, wave = tid >> 6;
  f32x4 acc[16] = {};

  const int lrow = tid>>2, lk = (tid&3)*16;
  int ar = m0 + lrow; if (ar > R-1) ar = R-1;

  for (int kt=0; kt<4; ++kt){
    // A-tile -> regs
    uint4 wa0, wa1;
    if (AF32){
      const float* p = (const float*)Ain + (long)ar*lda + kt*64 + lk;
      wa0 = pk8(*(const float4*)(p+0), *(const float4*)(p+4));
      wa1 = pk8(*(const float4*)(p+8), *(const float4*)(p+12));
    } else {
      const u16* p = (const u16*)Ain + (long)ar*lda + kt*64 + lk;
      wa0 = *(const uint4*)p; wa1 = *(const uint4*)(p+8);
    }
    // W rows -> regs (thread t loads W[t][kt*64..+63]); L2-resident after first blocks
    uint4 wb[8];
    {
      const float* wp = W + (long)tid*256 + kt*64;
      #pragma unroll
      for (int i=0;i<8;i++)
        wb[i] = pk8(*(const float4*)(wp + i*8), *(const float4*)(wp + i*8 + 4));
    }
    __syncthreads();   // prior tile fully consumed
    *(uint4*)&As[lrow][lk] = wa0; *(uint4*)&As[lrow][lk+8] = wa1;
    #pragma unroll
    for (int i=0;i<8;i++) *(uint4*)&Bs[tid][i*8] = wb[i];
    __syncthreads();
    #pragma unroll
    for (int kk=0; kk<2; ++kk){
      const int ko = kk*32 + (lane>>4)*8;
      bf16x8 af = *(const bf16x8*)&As[wave*16 + (lane&15)][ko];
      #pragma unroll
      for (int jj=0; jj<16; jj++){
        bf16x8 bfr = *(const bf16x8*)&Bs[jj*16 + (lane&15)][ko];
        acc[jj] = __builtin_amdgcn_mfma_f32_16x16x32_bf16(af, bfr, acc[jj], 0,0,0);
      }
    }
  }

  // epilogue: per-row ssq over 256 cols = 16 local (jj) + 16 lanes (xor 1,2,4,8)
  #pragma unroll
  for (int r=0;r<4;r++){
    float ssq = 0.f;
    #pragma unroll
    for (int jj=0;jj<16;jj++) ssq += acc[jj][r]*acc[jj][r];
    ssq += __shfl_xor(ssq,1); ssq += __shfl_xor(ssq,2);
    ssq += __shfl_xor(ssq,4); ssq += __shfl_xor(ssq,8);
    float inv = 1.0f/fmaxf(sqrtf(ssq), 1e-6f);
    int row = m0 + wave*16 + (lane>>4)*4 + r;
    if (row < R){
      u16* op = outp + (long)row*256 + (lane&15);
      #pragma unroll
      for (int jj=0;jj<16;jj++) op[jj*16] = f2b(acc[jj][r]*inv);
    }
  }
}

// ---------------------------------------------------------------------------
// Exact top-RANK of a 16384-long row. Bitwise rank-select on order-preserving
// keys + index tie-break (smallest indices first) == jax.lax.top_k's set.
// Early exit: if count(>= cand) == RANK at any prefix, {k >= cand} IS the
// top-RANK set -> skip remaining bits AND the tie-break.
// Element mapping (vectorized load): e(j) = tid*4 + (j&3) + (j>>2)*1024.
// ---------------------------------------------------------------------------
__global__ __launch_bounds__(256) void topk_kernel(const float* inF, const unsigned* inK,
    long in_stride, int RANK, float* out_val, int* out_idx)
{
  __shared__ int red[2][4];
  __shared__ int redt[4];
  __shared__ int poss;
  int row = blockIdx.x, tid = threadIdx.x;
  unsigned kr[64];
  if (inF){
    const float4* p = (const float4*)(inF + (long)row*in_stride);
    #pragma unroll
    for (int jj=0;jj<16;jj++){
      float4 v = p[tid + jj*256];
      kr[jj*4+0]=fkey(v.x); kr[jj*4+1]=fkey(v.y); kr[jj*4+2]=fkey(v.z); kr[jj*4+3]=fkey(v.w);
    }
  } else {
    const uint4* p = (const uint4*)(inK + (long)row*in_stride);
    #pragma unroll
    for (int jj=0;jj<16;jj++){
      uint4 v = p[tid + jj*256];
      kr[jj*4+0]=v.x; kr[jj*4+1]=v.y; kr[jj*4+2]=v.z; kr[jj*4+3]=v.w;
    }
  }
  if (tid==0) poss = 0;

  unsigned u = 0; bool exact = false; int pp = 0;
  for (int bit=31; bit>=0; --bit){
    unsigned cand = u | (1u<<bit);
    int c = 0;
    #pragma unroll
    for (int j=0;j<64;j++) c += (kr[j] >= cand) ? 1 : 0;
    #pragma unroll
    for (int off=32; off; off>>=1) c += __shfl_down(c, off);
    if ((tid&63)==0) red[pp][tid>>6] = c;
    __syncthreads();
    c = red[pp][0]+red[pp][1]+red[pp][2]+red[pp][3];
    pp ^= 1;
    if (c >= RANK){
      u = cand;
      if (c == RANK){ exact = true; break; }   // uniform decision -> safe break
    }
  }

  int t = 0;
  if (!exact){
    int cgt = 0;
    #pragma unroll
    for (int j=0;j<64;j++) cgt += (kr[j] > u) ? 1 : 0;
    #pragma unroll
    for (int off=32; off; off>>=1) cgt += __shfl_down(cgt, off);
    __syncthreads();
    if ((tid&63)==0) redt[tid>>6] = cgt;
    __syncthreads();
    cgt = redt[0]+redt[1]+redt[2]+redt[3];
    int Req = RANK - cgt;   // >=1 always
    for (int bit=13; bit>=0; --bit){
      int cand = t | (1<<bit);
      int c = 0;
      #pragma unroll
      for (int j=0;j<64;j++){
        int e = (tid<<2) + (j&3) + ((j>>2)<<10);
        c += (kr[j]==u && e < cand) ? 1 : 0;
      }
      #pragma unroll
      for (int off=32; off; off>>=1) c += __shfl_down(c, off);
      __syncthreads();
      if ((tid&63)==0) redt[tid>>6] = c;
      __syncthreads();
      c = redt[0]+redt[1]+redt[2]+redt[3];
      if (c < Req) t = cand;
    }
  }
  __syncthreads();
  #pragma unroll
  for (int j=0;j<64;j++){
    int e = (tid<<2) + (j&3) + ((j>>2)<<10);
    unsigned kk = kr[j];
    bool win = exact ? (kk >= u) : (kk > u || (kk == u && e <= t));
    if (win){
      int p2 = atomicAdd(&poss, 1);
      out_val[(long)row*RANK + p2] = funkey(kk);
      out_idx[(long)row*RANK + p2] = e;
    }
  }
}

// ---------------------------------------------------------------------------
// aligned[row,:] = softmax(vals96) . memory[b, idx96, :]   (memory fp32)
// ---------------------------------------------------------------------------
__global__ __launch_bounds__(256) void align_combine(const float* vals, const int* idx,
    const float* memory, float* alignedv)
{
  __shared__ float w[96];
  __shared__ int id[96];
  __shared__ float reds[2];
  int row = blockIdx.x, tid = threadIdx.x;
  int b = row / 200;
  if (tid < 96){ w[tid] = vals[(long)row*96 + tid]; id[tid] = idx[(long)row*96 + tid]; }
  __syncthreads();
  if (tid < 64){
    float a = w[tid];
    float bb2 = (tid < 32) ? w[64+tid] : -3e38f;
    float m = fmaxf(a, bb2);
    #pragma unroll
    for (int off=32; off; off>>=1) m = fmaxf(m, __shfl_xor(m, off));
    if (tid==0) reds[0] = m;
  }
  __syncthreads();
  float m = reds[0];
  if (tid < 96) w[tid] = __expf(w[tid]-m);
  __syncthreads();
  if (tid < 64){
    float a = w[tid] + ((tid<32)? w[64+tid] : 0.f);
    #pragma unroll
    for (int off=32; off; off>>=1) a += __shfl_xor(a, off);
    if (tid==0) reds[1] = a;
  }
  __syncthreads();
  float invs = 1.0f/reds[1];
  float acc = 0.f;
  const float* mb = memory + (long)b*K_*D_;
  for (int k=0;k<96;k++) acc += w[k] * mb[(long)id[k]*D_ + tid];
  alignedv[(long)row*256 + tid] = acc*invs;
}

__global__ void make_cat(const float* q, const float* alignedv, u16* cat)
{
  int row = blockIdx.x, tid = threadIdx.x;
  long i = (long)row*256 + tid;
  cat[(long)row*512 + tid]       = f2b(q[i]);
  cat[(long)row*512 + 256 + tid] = f2b(alignedv[i]);
}

__global__ void combine_gate(const float* q, const float* q_pos, const float* alignedv,
    const float* gate, float* qx, u16* qx_b, u16* qk_b)
{
  int row = blockIdx.x, tid = threadIdx.x;
  long i = (long)row*256 + tid;
  float v = q[i] + gate[i]*alignedv[i];
  qx[i] = v;
  qx_b[i] = f2b(v);
  qk_b[i] = f2b(v + q_pos[i]);
}

// ---------------------------------------------------------------------------
// t = x + y; LN over D=256 (biased var, eps 1e-5). Optional outputs.
// fminf/fmaxf launder NaN (return the non-NaN operand) -> finite diagnostics.
// ---------------------------------------------------------------------------
__global__ __launch_bounds__(256) void add_ln(const float* x, const float* y,
    const float* g, const float* bb, const float* q_pos,
    float* out_f, u16* out_b, u16* out_pos_b)
{
  __shared__ float red[8];
  int row = blockIdx.x, tid = threadIdx.x;
  long i = (long)row*256 + tid;
  float t = fminf(fmaxf(x[i] + y[i], -1e6f), 1e6f);
  float s1 = t, s2 = t*t;
  #pragma unroll
  for (int off=32; off; off>>=1){ s1 += __shfl_down(s1,off); s2 += __shfl_down(s2,off); }
  if ((tid&63)==0){ red[(tid>>6)*2] = s1; red[(tid>>6)*2+1] = s2; }
  __syncthreads();
  s1 = red[0]+red[2]+red[4]+red[6];
  s2 = red[1]+red[3]+red[5]+red[7];
  float mu = s1 * (1.0f/256.0f);
  float var = fmaxf(s2 * (1.0f/256.0f) - mu*mu, 0.f);
  float rstd = rsqrtf(var + 1e-5f);
  float v = (t-mu)*rstd*g[tid] + bb[tid];
  if (out_f) out_f[i] = v;
  if (out_b) out_b[i] = f2b(v);
  if (out_pos_b) out_pos_b[i] = f2b(v + q_pos[i]);
}

__global__ void fill_u32(unsigned* p, unsigned val, int n)
{ int i = blockIdx.x*256 + threadIdx.x; if (i<n) p[i] = val; }

// ---------------------------------------------------------------------------
// Pre-gather cross-attn bias into dense biasT[b][j][q] (j = position in kidx).
// ---------------------------------------------------------------------------
__global__ __launch_bounds__(256) void bias_gather(const float* cbias, const int* kidx,
    float* biasT)
{
  int b = blockIdx.y;
  int j = blockIdx.x*8 + (threadIdx.x>>5);
  int q = threadIdx.x & 31;
  int kid = kidx[b*CROSSK_ + j];
  const float* src = cbias + (long)b*Q_*K_ + kid;
  float* dst = biasT + ((long)b*CROSSK_ + j)*200;
  for (int qq=q; qq<200; qq+=32) dst[qq] = src[(long)qq*K_];
}

// ---------------------------------------------------------------------------
// Fused MHA, flash-style with KV-split (flash-decoding). One block per
// (b, h, 64-q-tile, kv-split). Scores kept in registers; each thread
// accumulates all 32 dims for its q-row quadrant, quad-reduced via shfl.
// Bias (cross) read from dense pre-gathered biasT[b][j][q].
// ---------------------------------------------------------------------------
__global__ __launch_bounds__(256) void attn_kernel(
    const u16* Qb, int q_stride,
    const u16* KVb, int kv_stride, int k_off, int v_off, int Lk,
    const float* biasT,
    int nsplit, int chunk,
    float* opart, float* mlpart, float scale)
{
  __shared__ float Ks[64][36];
  __shared__ float Vs[64][36];
  const int b = blockIdx.z, h = blockIdx.y;
  const int split = blockIdx.x % nsplit;
  const int q0 = (blockIdx.x / nsplit) * 64;
  const int tid = threadIdx.x;
  const int cg = tid & 3, r = tid >> 2;
  const int kbeg = split*chunk;
  int kend = kbeg + chunk; if (kend > Lk) kend = Lk;

  int qr = q0 + r; if (qr > 199) qr = 199;
  float qreg[32];
  {
    const u16* qp = Qb + (long)(b*200+qr)*q_stride + h*32;
    #pragma unroll
    for (int w=0; w<4; w++){
      uint4 u = *(const uint4*)(qp + w*8);
      qreg[w*8+0]=b2f((u16)(u.x&0xffffu))*scale; qreg[w*8+1]=b2f((u16)(u.x>>16))*scale;
      qreg[w*8+2]=b2f((u16)(u.y&0xffffu))*scale; qreg[w*8+3]=b2f((u16)(u.y>>16))*scale;
      qreg[w*8+4]=b2f((u16)(u.z&0xffffu))*scale; qreg[w*8+5]=b2f((u16)(u.z>>16))*scale;
      qreg[w*8+6]=b2f((u16)(u.w&0xffffu))*scale; qreg[w*8+7]=b2f((u16)(u.w>>16))*scale;
    }
  }
  const float* bT = biasT ? biasT + ((long)b*CROSSK_)*200 + qr : nullptr;

  float o32[32];
  #pragma unroll
  for (int i=0;i<32;i++) o32[i]=0.f;
  float mrun = -3e38f, lrun = 0.f;

  const int srow = tid>>2, sc8 = (tid&3)*8;   // staging: 1 uint4 per matrix
  for (int j0=kbeg; j0<kend; j0+=64){
    int kr = j0 + srow; if (kr > kend-1) kr = kend-1;
    const long base = (long)(b*Lk + kr)*kv_stride;
    uint4 ku = *(const uint4*)(KVb + base + k_off + sc8);
    uint4 vu = *(const uint4*)(KVb + base + v_off + sc8);
    __syncthreads();   // prior tile fully consumed
    {
      float4 f0, f1;
      f0.x=b2f((u16)(ku.x&0xffffu)); f0.y=b2f((u16)(ku.x>>16)); f0.z=b2f((u16)(ku.y&0xffffu)); f0.w=b2f((u16)(ku.y>>16));
      f1.x=b2f((u16)(ku.z&0xffffu)); f1.y=b2f((u16)(ku.z>>16)); f1.z=b2f((u16)(ku.w&0xffffu)); f1.w=b2f((u16)(ku.w>>16));
      *(float4*)&Ks[srow][sc8] = f0; *(float4*)&Ks[srow][sc8+4] = f1;
      f0.x=b2f((u16)(vu.x&0xffffu)); f0.y=b2f((u16)(vu.x>>16)); f0.z=b2f((u16)(vu.y&0xffffu)); f0.w=b2f((u16)(vu.y>>16));
      f1.x=b2f((u16)(vu.z&0xffffu)); f1.y=b2f((u16)(vu.z>>16)); f1.z=b2f((u16)(vu.w&0xffffu)); f1.w=b2f((u16)(vu.w>>16));
      *(float4*)&Vs[srow][sc8] = f0; *(float4*)&Vs[srow][sc8+4] = f1;
    }
    __syncthreads();

    float sv[16];
    float mloc = -3e38f;
    #pragma unroll
    for (int jj=0;jj<16;jj++){
      const int c = cg + jj*4;
      const float4* kp = (const float4*)&Ks[c][0];
      float a = 0.f;
      #pragma unroll
      for (int dq=0;dq<8;dq++){
        float4 kv = kp[dq];
        a += qreg[dq*4+0]*kv.x + qreg[dq*4+1]*kv.y + qreg[dq*4+2]*kv.z + qreg[dq*4+3]*kv.w;
      }
      if (biasT) a += bT[(long)(j0 + c)*200];
      if (j0 + c >= kend) a = -3e38f;
      sv[jj] = a; mloc = fmaxf(mloc, a);
    }
    mloc = fmaxf(mloc, __shfl_xor(mloc,1));
    mloc = fmaxf(mloc, __shfl_xor(mloc,2));
    const float mnew = fmaxf(mrun, mloc);
    const float alpha = __expf(mrun - mnew);
    float lloc = 0.f;
    #pragma unroll
    for (int jj=0;jj<16;jj++){
      float p = (j0 + cg + jj*4 >= kend) ? 0.f : __expf(sv[jj]-mnew);
      sv[jj] = p; lloc += p;
    }
    lloc += __shfl_xor(lloc,1);
    lloc += __shfl_xor(lloc,2);
    lrun = lrun*alpha + lloc;
    #pragma unroll
    for (int i=0;i<32;i++) o32[i] *= alpha;
    #pragma unroll
    for (int jj=0;jj<16;jj++){
      const int c = cg + jj*4;
      const float p = sv[jj];
      const float4* vp = (const float4*)&Vs[c][0];
      #pragma unroll
      for (int dq=0;dq<8;dq++){
        float4 v = vp[dq];
        o32[dq*4+0] += p*v.x; o32[dq*4+1] += p*v.y; o32[dq*4+2] += p*v.z; o32[dq*4+3] += p*v.w;
      }
    }
    mrun = mnew;
  }

  #pragma unroll
  for (int d=0;d<32;d++){
    float v = o32[d];
    v += __shfl_xor(v,1);
    v += __shfl_xor(v,2);
    o32[d] = v;
  }
  if (q0 + r < 200){
    const long pbase = (((long)(b*H_+h)*nsplit + split)*200) + (q0 + r);
    float* op = opart + pbase*32;
    #pragma unroll
    for (int i=0;i<8;i++) op[cg*8+i] = o32[cg*8+i];
    if (cg==0){ mlpart[pbase*2] = mrun; mlpart[pbase*2+1] = lrun; }
  }
}

// Combine KV-split partials: out = sum_s o_s*exp(m_s-M) / sum_s l_s*exp(m_s-M)
__global__ __launch_bounds__(256) void attn_combine(const float* opart, const float* mlpart,
    int nsplit, u16* outp)
{
  int row = blockIdx.x;                 // 0..BQ_-1
  int b = row/200, qi = row%200;
  int tid = threadIdx.x;
  int h = tid>>5, d = tid&31;
  const long base = ((long)(b*H_+h)*nsplit)*200 + qi;   // + s*200 per split
  float M = -3e38f;
  for (int s=0;s<nsplit;s++) M = fmaxf(M, mlpart[(base + (long)s*200)*2]);
  float L = 0.f, acc = 0.f;
  for (int s=0;s<nsplit;s++){
    const long ix = base + (long)s*200;
    float w = __expf(mlpart[ix*2] - M);
    L   += mlpart[ix*2+1]*w;
    acc += opart[ix*32 + d]*w;
  }
  outp[(long)row*256 + h*32 + d] = f2b(acc / fmaxf(L, 1e-30f));
}

// ---------------------------------------------------------------------------
extern "C" void kernel_launch(void* const* d_in, const int* in_sizes, int n_in,
                              void* d_out, int out_size, void* d_ws, size_t ws_size,
                              hipStream_t stream)
{
  const float* q        = (const float*)d_in[0];
  const float* q_pos    = (const float*)d_in[1];
  const float* memory   = (const float*)d_in[2];
  const float* cbias    = (const float*)d_in[3];
  const float* align_wq = (const float*)d_in[4];
  const float* align_wm = (const float*)d_in[5];
  const float* gate_w1  = (const float*)d_in[6];
  const float* gate_b1  = (const float*)d_in[7];
  const float* gate_w2  = (const float*)d_in[8];
  const float* gate_b2  = (const float*)d_in[9];
  const float* cross_wq = (const float*)d_in[10];
  const float* cross_wm = (const float*)d_in[11];
  const float* sa_in_w  = (const float*)d_in[12];
  const float* sa_in_b  = (const float*)d_in[13];
  const float* sa_out_w = (const float*)d_in[14];
  const float* sa_out_b = (const float*)d_in[15];
  const float* ca_in_w  = (const float*)d_in[16];
  const float* ca_in_b  = (const float*)d_in[17];
  const float* ca_out_w = (const float*)d_in[18];
  const float* ca_out_b = (const float*)d_in[19];
  const float* ffn_w1   = (const float*)d_in[20];
  const float* ffn_b1   = (const float*)d_in[21];
  const float* ffn_w2   = (const float*)d_in[22];
  const float* ffn_b2   = (const float*)d_in[23];
  const float* n1_g = (const float*)d_in[24];
  const float* n1_b = (const float*)d_in[25];
  const float* n2_g = (const float*)d_in[26];
  const float* n2_b = (const float*)d_in[27];
  const float* n3_g = (const float*)d_in[28];
  const float* n3_b = (const float*)d_in[29];
  float* out = (float*)d_out;   // reference output dtype is fp32

  // ---- workspace layout, fitted to ws_size (deterministic per call) ----
  char* wsb = (char*)d_ws;
  size_t off = 0;
  auto alloc = [&](size_t bytes)->char*{
    char* p = wsb + off; off = (off + bytes + 255) & ~(size_t)255; return p;
  };
  const int NSPLIT = 4;   // KV splits for both attentions
  // small fixed buffers (~36 MB)
  u16*    qn_bf   = (u16*)   alloc((size_t)BQ_*D_*2);
  float*  vals96  = (float*) alloc((size_t)BQ_*96*4);
  int*    idx96   = (int*)   alloc((size_t)BQ_*96*4);
  float*  alignedv= (float*) alloc((size_t)BQ_*D_*4);
  u16*    cat_bf  = (u16*)   alloc((size_t)BQ_*512*2);
  u16*    h_bf    = (u16*)   alloc((size_t)BQ_*D_*2);
  float*  gatebuf = (float*) alloc((size_t)BQ_*D_*4);
  float*  qx      = (float*) alloc((size_t)BQ_*D_*4);
  u16*    qx_bf   = (u16*)   alloc((size_t)BQ_*D_*2);
  u16*    qk_bf   = (u16*)   alloc((size_t)BQ_*D_*2);
  u16*    qpos2_bf= (u16*)   alloc((size_t)BQ_*D_*2);
  u16*    qkv_bf  = (u16*)   alloc((size_t)BQ_*768*2);
  u16*    attO_bf = (u16*)   alloc((size_t)BQ_*D_*2);
  float*  q2      = (float*) alloc((size_t)BQ_*D_*4);
  unsigned* imp   = (unsigned*)alloc((size_t)B_*K_*4);
  int*    kidx    = (int*)   alloc((size_t)B_*CROSSK_*4);
  u16*    cq_bf   = (u16*)   alloc((size_t)BQ_*D_*2);
  u16*    f1_bf   = (u16*)   alloc((size_t)BQ_*FF_*2);
  float*  f2buf   = (float*) alloc((size_t)BQ_*D_*4);
  float*  opart   = (float*) alloc((size_t)B_*H_*NSPLIT*200*32*4);  // 6.6 MB
  float*  mlpart  = (float*) alloc((size_t)B_*H_*NSPLIT*200*2*4);   // 0.4 MB
  float*  biasT   = (float*) alloc((size_t)B_*CROSSK_*200*4);       // 6.6 MB

  // big buffers: mn (>= kvbuf size, kvbuf aliases it) and simbuf
  const size_t kv_bytes   = (size_t)B_*CROSSK_*512*2;        // 8.4 MB
  const size_t mn_full    = (size_t)BK_*D_*2;                // 67 MB
  const size_t mn_small   = (size_t)K_*D_*2;                 // 8.4 MB
  const size_t sim_full   = (size_t)BQ_*K_*4;                // 105 MB
  size_t remain = (ws_size > off) ? ws_size - off : 0;
  bool fullws = remain >= mn_full + sim_full + (1u<<20);
  size_t mn_bytes = fullws ? mn_full : (mn_small > kv_bytes ? mn_small : kv_bytes);
  int simRows;                      // rows of sim materialized at once
  if (fullws) simRows = BQ_;
  else {
    size_t left = (remain > mn_bytes + (1u<<18)) ? remain - mn_bytes - (1u<<18) : 0;
    long r = (long)(left / ((size_t)K_*4));
    simRows = (int)(r < 8 ? 8 : (r > Q_ ? Q_ : r));
  }
  u16*   mn_bf  = (u16*)  alloc(mn_bytes);
  u16*   kvbuf  = (u16*)  mn_bf;     // alias: mn dead before kvbuf is written
  float* simbuf = (float*)alloc((size_t)simRows*K_*4);

  auto gemm = [&](int af32, int bf32,
                  const void* A, long lda, long sA,
                  const void* Bm, long ldb, long sB,
                  int M, int N, int Kd,
                  const float* bias, int act,
                  float* Cf, u16* Cb, long ldc, long sC,
                  unsigned* amax, long sAmax,
                  const int* gather, long sGather, int Z){
    GArgs ga;
    ga.A=A; ga.B=Bm; ga.bias=bias; ga.Cf=Cf; ga.Cb=Cb; ga.amax=amax; ga.gather=gather;
    ga.lda=lda; ga.ldb=ldb; ga.ldc=ldc; ga.sA=sA; ga.sB=sB; ga.sC=sC;
    ga.sAmax=sAmax; ga.sGather=sGather;
    ga.M=M; ga.N=N; ga.K=Kd; ga.act=act;
    dim3 grid(N/64, (M+63)/64, Z);
    if (af32 && bf32)      gemm_bt<1,1><<<grid, 256, 0, stream>>>(ga);
    else if (af32)         gemm_bt<1,0><<<grid, 256, 0, stream>>>(ga);
    else if (bf32)         gemm_bt<0,1><<<grid, 256, 0, stream>>>(ga);
    else                   gemm_bt<0,0><<<grid, 256, 0, stream>>>(ga);
  };
  const float ascale = 0.17677669529663687f;  // 1/sqrt(32)

  // --- align: fused projection+l2norm + sim + top-96 ---
  proj_l2norm<1><<<BQ_/64,256,0,stream>>>(q, 256, align_wq, qn_bf, BQ_);
  if (fullws){
    proj_l2norm<1><<<BK_/64,256,0,stream>>>(memory, 256, align_wm, mn_bf, BK_);
    gemm(0,0, qn_bf,256,(long)200*256, mn_bf,256,(long)K_*256, 200,K_,256,
         nullptr,0, simbuf,nullptr,K_,(long)200*K_, nullptr,0, nullptr,0, B_);
    topk_kernel<<<BQ_,256,0,stream>>>(simbuf, nullptr, K_, 96, vals96, idx96);
  } else {
    for (int b=0;b<B_;b++){
      proj_l2norm<1><<<K_/64,256,0,stream>>>(memory + (size_t)b*K_*256, 256, align_wm, mn_bf, K_);
      for (int q0=0; q0<Q_; q0+=simRows){
        int rows = (Q_ - q0 < simRows) ? (Q_ - q0) : simRows;
        gemm(0,0, qn_bf + ((size_t)b*200+q0)*256,256,0, mn_bf,256,0, rows,K_,256,
             nullptr,0, simbuf,nullptr,K_,0, nullptr,0, nullptr,0, 1);
        topk_kernel<<<rows,256,0,stream>>>(simbuf, nullptr, K_, 96,
             vals96 + ((size_t)b*200+q0)*96, idx96 + ((size_t)b*200+q0)*96);
      }
    }
  }
  align_combine<<<BQ_,256,0,stream>>>(vals96, idx96, memory, alignedv);

  // --- gate MLP ---
  make_cat<<<BQ_,256,0,stream>>>(q, alignedv, cat_bf);
  gemm(0,1, cat_bf,512,0, gate_w1,512,0, BQ_,256,512, gate_b1,1, nullptr,h_bf,256,0, nullptr,0, nullptr,0, 1);
  gemm(0,1, h_bf,256,0, gate_w2,256,0, BQ_,256,256, gate_b2,2, gatebuf,nullptr,256,0, nullptr,0, nullptr,0, 1);
  combine_gate<<<BQ_,256,0,stream>>>(q, q_pos, alignedv, gatebuf, qx, qx_bf, qk_bf);

  // --- self attention (KV-split: 4 chunks of 64 over Lk=200) ---
  gemm(0,1, qk_bf,256,0, sa_in_w,256,0, BQ_,512,256, sa_in_b,0, nullptr,qkv_bf,768,0, nullptr,0, nullptr,0, 1);
  gemm(0,1, qx_bf,256,0, sa_in_w+512*256,256,0, BQ_,256,256, sa_in_b+512,0, nullptr,qkv_bf+512,768,0, nullptr,0, nullptr,0, 1);
  attn_kernel<<<dim3(4*NSPLIT,H_,B_),256,0,stream>>>(qkv_bf,768, qkv_bf,768,256,512,200,
      nullptr, NSPLIT,64, opart,mlpart, ascale);
  attn_combine<<<BQ_,256,0,stream>>>(opart, mlpart, NSPLIT, attO_bf);
  gemm(0,1, attO_bf,256,0, sa_out_w,256,0, BQ_,256,256, sa_out_b,0, q2,nullptr,256,0, nullptr,0, nullptr,0, 1);
  add_ln<<<BQ_,256,0,stream>>>(qx, q2, n1_g, n1_b, q_pos, qx, qx_bf, qpos2_bf);

  // --- cross-memory sparsify (importance = max over Q of sim2, then top-1024) ---
  proj_l2norm<0><<<BQ_/64,256,0,stream>>>(qx_bf, 256, cross_wq, qn_bf, BQ_);
  fill_u32<<<(B_*K_+255)/256,256,0,stream>>>(imp, 0u, B_*K_);
  if (fullws){
    proj_l2norm<1><<<BK_/64,256,0,stream>>>(memory, 256, cross_wm, mn_bf, BK_);
    gemm(0,0, qn_bf,256,(long)200*256, mn_bf,256,(long)K_*256, 200,K_,256,
         nullptr,0, nullptr,nullptr,0,0, imp,(long)K_, nullptr,0, B_);
  } else {
    for (int b=0;b<B_;b++){
      proj_l2norm<1><<<K_/64,256,0,stream>>>(memory + (size_t)b*K_*256, 256, cross_wm, mn_bf, K_);
      gemm(0,0, qn_bf + (size_t)b*200*256,256,0, mn_bf,256,0, 200,K_,256,
           nullptr,0, nullptr,nullptr,0,0, imp + (size_t)b*K_,(long)K_, nullptr,0, 1);
    }
  }
  topk_kernel<<<B_,256,0,stream>>>(nullptr, imp, K_, CROSSK_, vals96 /*scratch*/, kidx);

  // --- cross attention (kvbuf aliases mn region; mn is dead now) ---
  bias_gather<<<dim3(CROSSK_/8, B_),256,0,stream>>>(cbias, kidx, biasT);
  gemm(1,1, memory,256,(long)K_*256, ca_in_w+256*256,256,0, CROSSK_,512,256,
       ca_in_b+256,0, nullptr,kvbuf,512,(long)CROSSK_*512, nullptr,0, kidx,(long)CROSSK_, B_);
  gemm(0,1, qpos2_bf,256,0, ca_in_w,256,0, BQ_,256,256, ca_in_b,0, nullptr,cq_bf,256,0, nullptr,0, nullptr,0, 1);
  attn_kernel<<<dim3(4*NSPLIT,H_,B_),256,0,stream>>>(cq_bf,256, kvbuf,512,0,256,CROSSK_,
      biasT, NSPLIT,256, opart,mlpart, ascale);
  attn_combine<<<BQ_,256,0,stream>>>(opart, mlpart, NSPLIT, attO_bf);
  gemm(0,1, attO_bf,256,0, ca_out_w,256,0, BQ_,256,256, ca_out_b,0, q2,nullptr,256,0, nullptr,0, nullptr,0, 1);
  add_ln<<<BQ_,256,0,stream>>>(qx, q2, n2_g, n2_b, nullptr, qx, qx_bf, nullptr);

  // --- FFN + final LN -> d_out (fp32) ---
  gemm(0,1, qx_bf,256,0, ffn_w1,256,0, BQ_,FF_,256, ffn_b1,1, nullptr,f1_bf,FF_,0, nullptr,0, nullptr,0, 1);
  gemm(0,1, f1_bf,FF_,0, ffn_w2,FF_,0, BQ_,256,FF_, ffn_b2,0, f2buf,nullptr,256,0, nullptr,0, nullptr,0, 1);
  add_ln<<<BQ_,256,0,stream>>>(qx, f2buf, n3_g, n3_b, nullptr, out, nullptr, nullptr);

  (void)in_sizes; (void)n_in; (void)out_size;
}

// Round 5
// 916.024 us; speedup vs baseline: 1.4008x; 1.0854x over previous
//
#include <hip/hip_runtime.h>
#include <hip/hip_bf16.h>
#include <math.h>

// Problem constants
#define B_ 8
#define Q_ 200
#define K_ 16384
#define D_ 256
#define H_ 8
#define DH_ 32
#define ALIGNK_ 96
#define CROSSK_ 1024
#define FF_ 1024
#define BQ_ (B_*Q_)     // 1600
#define BK_ (B_*K_)     // 131072

typedef unsigned short u16;
typedef short bf16x8 __attribute__((ext_vector_type(8)));
typedef float f32x4 __attribute__((ext_vector_type(4)));

__device__ __forceinline__ float b2f(u16 u){ return __uint_as_float(((unsigned)u)<<16); }
__device__ __forceinline__ u16 f2b(float f){
  unsigned x = __float_as_uint(f);
  unsigned r = x + 0x7FFFu + ((x>>16)&1u);   // round-to-nearest-even
  return (u16)(r>>16);
}
__device__ __forceinline__ unsigned p2u(float lo, float hi){
  return (unsigned)f2b(lo) | ((unsigned)f2b(hi)<<16);
}
__device__ __forceinline__ uint4 pk8(float4 a, float4 b){
  return make_uint4(p2u(a.x,a.y), p2u(a.z,a.w), p2u(b.x,b.y), p2u(b.z,b.w));
}
// order-preserving float->uint key (larger float => larger key)
__device__ __forceinline__ unsigned fkey(float f){ unsigned b=__float_as_uint(f); return (b&0x80000000u)? ~b : (b|0x80000000u); }
__device__ __forceinline__ float funkey(unsigned k){ unsigned b=(k&0x80000000u)? (k^0x80000000u) : ~k; return __uint_as_float(b); }
__device__ __forceinline__ float gelu_f(float x){ return 0.5f*x*(1.0f+erff(x*0.70710678118654752f)); }
__device__ __forceinline__ float sigmoid_f(float x){ return 1.0f/(1.0f+__expf(-x)); }

// ---------------------------------------------------------------------------
// General NT GEMM:  C[m,n] = sum_k A[m,k]*B[n,k]  (fp32 acc). A/B each either
// fp32 (converted to bf16 in registers) or bf16. Tile 64x64, BK=64, 4 waves.
// Modes: optional fp32 bias[n], act (1=gelu,2=sigmoid), out fp32 or bf16,
//        per-column atomic-max (importance), optional A-row gather.
// ---------------------------------------------------------------------------
struct GArgs {
  const void* A; const void* B; const float* bias;
  float* Cf; u16* Cb; unsigned* amax;
  const int* gather;
  long lda, ldb, ldc;
  long sA, sB, sC, sAmax, sGather;
  int M, N, K, act;
};

template<int AF32, int BF32>
__global__ __launch_bounds__(256) void gemm_bt(GArgs g)
{
  const int tid = threadIdx.x;
  const int bz = blockIdx.z;
  const int m0 = blockIdx.y*64, n0 = blockIdx.x*64;
  const int lane = tid & 63, wave = tid >> 6;
  const int wr = wave >> 1, wc = wave & 1;
  __shared__ __align__(16) u16 As[64][72];
  __shared__ __align__(16) u16 Bs[64][72];
  f32x4 acc[2][2] = {};

  const int lrow = tid>>2;
  const int lk = (tid&3)*16;
  int ar = m0 + lrow; if (ar > g.M-1) ar = g.M-1;
  if (g.gather) ar = g.gather[(long)bz*g.sGather + ar];
  int br = n0 + lrow; if (br > g.N-1) br = g.N-1;
  long aoff = (long)bz*g.sA + (long)ar*g.lda + lk;
  long boff = (long)bz*g.sB + (long)br*g.ldb + lk;

  const int nk = g.K >> 6;
  for (int kt=0; kt<nk; ++kt){
    uint4 wa0, wa1, wb0, wb1;
    if (AF32){
      const float* p = (const float*)g.A + aoff;
      float4 f0 = *(const float4*)(p+0);
      float4 f1 = *(const float4*)(p+4);
      float4 f2v= *(const float4*)(p+8);
      float4 f3 = *(const float4*)(p+12);
      wa0 = pk8(f0,f1); wa1 = pk8(f2v,f3);
    } else {
      const u16* p = (const u16*)g.A + aoff;
      wa0 = *(const uint4*)p; wa1 = *(const uint4*)(p+8);
    }
    if (BF32){
      const float* p = (const float*)g.B + boff;
      float4 f0 = *(const float4*)(p+0);
      float4 f1 = *(const float4*)(p+4);
      float4 f2v= *(const float4*)(p+8);
      float4 f3 = *(const float4*)(p+12);
      wb0 = pk8(f0,f1); wb1 = pk8(f2v,f3);
    } else {
      const u16* p = (const u16*)g.B + boff;
      wb0 = *(const uint4*)p; wb1 = *(const uint4*)(p+8);
    }
    aoff += 64; boff += 64;
    __syncthreads();
    *(uint4*)&As[lrow][lk]   = wa0; *(uint4*)&As[lrow][lk+8] = wa1;
    *(uint4*)&Bs[lrow][lk]   = wb0; *(uint4*)&Bs[lrow][lk+8] = wb1;
    __syncthreads();
    #pragma unroll
    for (int kk=0; kk<2; ++kk){
      const int ko = kk*32 + (lane>>4)*8;
      bf16x8 af0 = *(const bf16x8*)&As[wr*32      + (lane&15)][ko];
      bf16x8 af1 = *(const bf16x8*)&As[wr*32 + 16 + (lane&15)][ko];
      bf16x8 bf0 = *(const bf16x8*)&Bs[wc*32      + (lane&15)][ko];
      bf16x8 bf1 = *(const bf16x8*)&Bs[wc*32 + 16 + (lane&15)][ko];
      acc[0][0] = __builtin_amdgcn_mfma_f32_16x16x32_bf16(af0, bf0, acc[0][0], 0,0,0);
      acc[0][1] = __builtin_amdgcn_mfma_f32_16x16x32_bf16(af0, bf1, acc[0][1], 0,0,0);
      acc[1][0] = __builtin_amdgcn_mfma_f32_16x16x32_bf16(af1, bf0, acc[1][0], 0,0,0);
      acc[1][1] = __builtin_amdgcn_mfma_f32_16x16x32_bf16(af1, bf1, acc[1][1], 0,0,0);
    }
  }

  if (g.amax){
    // per-column max over rows (M-clamp duplicates a valid row -> max unaffected)
    #pragma unroll
    for (int j=0;j<2;j++){
      float mx = -3.0e38f;
      #pragma unroll
      for (int i=0;i<2;i++)
        #pragma unroll
        for (int r=0;r<4;r++) mx = fmaxf(mx, acc[i][j][r]);
      mx = fmaxf(mx, __shfl_xor(mx, 16));
      mx = fmaxf(mx, __shfl_xor(mx, 32));
      if ((lane>>4)==0){
        int n = n0 + wc*32 + j*16 + (lane&15);
        if (n < g.N) atomicMax(&g.amax[(long)bz*g.sAmax + n], fkey(mx));
      }
    }
    return;
  }

  #pragma unroll
  for (int i=0;i<2;i++)
  #pragma unroll
  for (int j=0;j<2;j++)
  #pragma unroll
  for (int r=0;r<4;r++){
    int m = m0 + wr*32 + i*16 + (lane>>4)*4 + r;   // C row = quad*4+reg
    int n = n0 + wc*32 + j*16 + (lane&15);          // C col = lane&15
    if (m < g.M && n < g.N){
      float v = acc[i][j][r];
      if (g.bias) v += g.bias[n];
      if (g.act==1) v = gelu_f(v);
      else if (g.act==2) v = sigmoid_f(v);
      long ci = (long)bz*g.sC + (long)m*g.ldc + n;
      if (g.Cf) g.Cf[ci] = v; else g.Cb[ci] = f2b(v);
    }
  }
}

// fp32 -> bf16 weight conversion (one-shot, 256x256 matrices)
__global__ void w2b_kernel(const float* w, u16* wb, int n)
{
  int i = (blockIdx.x*256 + threadIdx.x)*8;
  if (i < n){
    float4 a = *(const float4*)(w+i), b = *(const float4*)(w+i+4);
    *(uint4*)(wb+i) = pk8(a,b);
  }
}

// ---------------------------------------------------------------------------
// Fused projection + row-L2-normalize (v2, occupancy-focused):
//   out[m,:] = l2norm( A[m,:] @ W.T )   A: [R][256] fp32 or bf16, W bf16 [256][256]
// Tile: 64 rows x 256 cols per block via inner nc-loop over 4 col-chunks.
// As[64][72] staged once per kt (A fetched ONCE per block); Bs[64][72]
// restaged per (kt,nc) from pre-converted bf16 W. LDS 18.4KB (vs 46KB in v1)
// -> ~4 blocks/CU (VGPR-capped) vs 3. Row norm in-registers, bf16 out direct.
// ---------------------------------------------------------------------------
template<int AF32>
__global__ __launch_bounds__(256) void proj_l2norm(
    const void* Ain, long lda, const u16* Wb, u16* outp, int R)
{
  __shared__ __align__(16) u16 As[64][72];
  __shared__ __align__(16) u16 Bs[64][72];
  const int tid = threadIdx.x;
  const int m0 = blockIdx.x*64;
  const int lane = tid & 63, wave = tid >> 6;
  f32x4 acc[4][4] = {};

  const int lrow = tid>>2, lk = (tid&3)*16;
  int ar = m0 + lrow; if (ar > R-1) ar = R-1;

  for (int kt=0; kt<4; ++kt){
    // A-chunk -> regs (once per kt)
    uint4 wa0, wa1;
    if (AF32){
      const float* p = (const float*)Ain + (long)ar*lda + kt*64 + lk;
      wa0 = pk8(*(const float4*)(p+0), *(const float4*)(p+4));
      wa1 = pk8(*(const float4*)(p+8), *(const float4*)(p+12));
    } else {
      const u16* p = (const u16*)Ain + (long)ar*lda + kt*64 + lk;
      wa0 = *(const uint4*)p; wa1 = *(const uint4*)(p+8);
    }
    #pragma unroll
    for (int nc=0; nc<4; ++nc){
      // W-chunk (bf16) -> regs; issued before barrier to overlap prior MFMAs
      const u16* wp = Wb + (long)(nc*64 + lrow)*256 + kt*64 + lk;
      uint4 wb0 = *(const uint4*)wp;
      uint4 wb1 = *(const uint4*)(wp+8);
      __syncthreads();   // prior stage fully consumed
      if (nc==0){ *(uint4*)&As[lrow][lk] = wa0; *(uint4*)&As[lrow][lk+8] = wa1; }
      *(uint4*)&Bs[lrow][lk] = wb0; *(uint4*)&Bs[lrow][lk+8] = wb1;
      __syncthreads();
      #pragma unroll
      for (int kk=0; kk<2; ++kk){
        const int ko = kk*32 + (lane>>4)*8;
        bf16x8 af = *(const bf16x8*)&As[wave*16 + (lane&15)][ko];
        #pragma unroll
        for (int j=0; j<4; j++){
          bf16x8 bfr = *(const bf16x8*)&Bs[j*16 + (lane&15)][ko];
          acc[nc][j] = __builtin_amdgcn_mfma_f32_16x16x32_bf16(af, bfr, acc[nc][j], 0,0,0);
        }
      }
    }
  }

  // epilogue: per-row ssq over 256 cols = 16 local (nc,j) + 16 lanes (xor 1,2,4,8)
  #pragma unroll
  for (int r=0;r<4;r++){
    float ssq = 0.f;
    #pragma unroll
    for (int nc=0;nc<4;nc++)
      #pragma unroll
      for (int j=0;j<4;j++) ssq += acc[nc][j][r]*acc[nc][j][r];
    ssq += __shfl_xor(ssq,1); ssq += __shfl_xor(ssq,2);
    ssq += __shfl_xor(ssq,4); ssq += __shfl_xor(ssq,8);
    float inv = 1.0f/fmaxf(sqrtf(ssq), 1e-6f);
    int row = m0 + wave*16 + (lane>>4)*4 + r;
    if (row < R){
      u16* op = outp + (long)row*256 + (lane&15);
      #pragma unroll
      for (int nc=0;nc<4;nc++)
        #pragma unroll
        for (int j=0;j<4;j++) op[nc*64 + j*16] = f2b(acc[nc][j][r]*inv);
    }
  }
}

// ---------------------------------------------------------------------------
// Exact top-RANK of a 16384-long row. Bitwise rank-select on order-preserving
// keys + index tie-break (smallest indices first) == jax.lax.top_k's set.
// Early exit: if count(>= cand) == RANK at any prefix, {k >= cand} IS the
// top-RANK set -> skip remaining bits AND the tie-break.
// Element mapping (vectorized load): e(j) = tid*4 + (j&3) + (j>>2)*1024.
// ---------------------------------------------------------------------------
__global__ __launch_bounds__(256) void topk_kernel(const float* inF, const unsigned* inK,
    long in_stride, int RANK, float* out_val, int* out_idx)
{
  __shared__ int red[2][4];
  __shared__ int redt[4];
  __shared__ int poss;
  int row = blockIdx.x, tid = threadIdx.x;
  unsigned kr[64];
  if (inF){
    const float4* p = (const float4*)(inF + (long)row*in_stride);
    #pragma unroll
    for (int jj=0;jj<16;jj++){
      float4 v = p[tid + jj*256];
      kr[jj*4+0]=fkey(v.x); kr[jj*4+1]=fkey(v.y); kr[jj*4+2]=fkey(v.z); kr[jj*4+3]=fkey(v.w);
    }
  } else {
    const uint4* p = (const uint4*)(inK + (long)row*in_stride);
    #pragma unroll
    for (int jj=0;jj<16;jj++){
      uint4 v = p[tid + jj*256];
      kr[jj*4+0]=v.x; kr[jj*4+1]=v.y; kr[jj*4+2]=v.z; kr[jj*4+3]=v.w;
    }
  }
  if (tid==0) poss = 0;

  unsigned u = 0; bool exact = false; int pp = 0;
  for (int bit=31; bit>=0; --bit){
    unsigned cand = u | (1u<<bit);
    int c = 0;
    #pragma unroll
    for (int j=0;j<64;j++) c += (kr[j] >= cand) ? 1 : 0;
    #pragma unroll
    for (int off=32; off; off>>=1) c += __shfl_down(c, off);
    if ((tid&63)==0) red[pp][tid>>6] = c;
    __syncthreads();
    c = red[pp][0]+red[pp][1]+red[pp][2]+red[pp][3];
    pp ^= 1;
    if (c >= RANK){
      u = cand;
      if (c == RANK){ exact = true; break; }   // uniform decision -> safe break
    }
  }

  int t = 0;
  if (!exact){
    int cgt = 0;
    #pragma unroll
    for (int j=0;j<64;j++) cgt += (kr[j] > u) ? 1 : 0;
    #pragma unroll
    for (int off=32; off; off>>=1) cgt += __shfl_down(cgt, off);
    __syncthreads();
    if ((tid&63)==0) redt[tid>>6] = cgt;
    __syncthreads();
    cgt = redt[0]+redt[1]+redt[2]+redt[3];
    int Req = RANK - cgt;   // >=1 always
    for (int bit=13; bit>=0; --bit){
      int cand = t | (1<<bit);
      int c = 0;
      #pragma unroll
      for (int j=0;j<64;j++){
        int e = (tid<<2) + (j&3) + ((j>>2)<<10);
        c += (kr[j]==u && e < cand) ? 1 : 0;
      }
      #pragma unroll
      for (int off=32; off; off>>=1) c += __shfl_down(c, off);
      __syncthreads();
      if ((tid&63)==0) redt[tid>>6] = c;
      __syncthreads();
      c = redt[0]+redt[1]+redt[2]+redt[3];
      if (c < Req) t = cand;
    }
  }
  __syncthreads();
  #pragma unroll
  for (int j=0;j<64;j++){
    int e = (tid<<2) + (j&3) + ((j>>2)<<10);
    unsigned kk = kr[j];
    bool win = exact ? (kk >= u) : (kk > u || (kk == u && e <= t));
    if (win){
      int p2 = atomicAdd(&poss, 1);
      out_val[(long)row*RANK + p2] = funkey(kk);
      out_idx[(long)row*RANK + p2] = e;
    }
  }
}

// ---------------------------------------------------------------------------
// aligned[row,:] = softmax(vals96) . memory[b, idx96, :]   (memory fp32)
// ---------------------------------------------------------------------------
__global__ __launch_bounds__(256) void align_combine(const float* vals, const int* idx,
    const float* memory, float* alignedv)
{
  __shared__ float w[96];
  __shared__ int id[96];
  __shared__ float reds[2];
  int row = blockIdx.x, tid = threadIdx.x;
  int b = row / 200;
  if (tid < 96){ w[tid] = vals[(long)row*96 + tid]; id[tid] = idx[(long)row*96 + tid]; }
  __syncthreads();
  if (tid < 64){
    float a = w[tid];
    float bb2 = (tid < 32) ? w[64+tid] : -3e38f;
    float m = fmaxf(a, bb2);
    #pragma unroll
    for (int off=32; off; off>>=1) m = fmaxf(m, __shfl_xor(m, off));
    if (tid==0) reds[0] = m;
  }
  __syncthreads();
  float m = reds[0];
  if (tid < 96) w[tid] = __expf(w[tid]-m);
  __syncthreads();
  if (tid < 64){
    float a = w[tid] + ((tid<32)? w[64+tid] : 0.f);
    #pragma unroll
    for (int off=32; off; off>>=1) a += __shfl_xor(a, off);
    if (tid==0) reds[1] = a;
  }
  __syncthreads();
  float invs = 1.0f/reds[1];
  float acc = 0.f;
  const float* mb = memory + (long)b*K_*D_;
  for (int k=0;k<96;k++) acc += w[k] * mb[(long)id[k]*D_ + tid];
  alignedv[(long)row*256 + tid] = acc*invs;
}

__global__ void make_cat(const float* q, const float* alignedv, u16* cat)
{
  int row = blockIdx.x, tid = threadIdx.x;
  long i = (long)row*256 + tid;
  cat[(long)row*512 + tid]       = f2b(q[i]);
  cat[(long)row*512 + 256 + tid] = f2b(alignedv[i]);
}

__global__ void combine_gate(const float* q, const float* q_pos, const float* alignedv,
    const float* gate, float* qx, u16* qx_b, u16* qk_b)
{
  int row = blockIdx.x, tid = threadIdx.x;
  long i = (long)row*256 + tid;
  float v = q[i] + gate[i]*alignedv[i];
  qx[i] = v;
  qx_b[i] = f2b(v);
  qk_b[i] = f2b(v + q_pos[i]);
}

// ---------------------------------------------------------------------------
// t = x + y; LN over D=256 (biased var, eps 1e-5). Optional outputs.
// fminf/fmaxf launder NaN (return the non-NaN operand) -> finite diagnostics.
// ---------------------------------------------------------------------------
__global__ __launch_bounds__(256) void add_ln(const float* x, const float* y,
    const float* g, const float* bb, const float* q_pos,
    float* out_f, u16* out_b, u16* out_pos_b)
{
  __shared__ float red[8];
  int row = blockIdx.x, tid = threadIdx.x;
  long i = (long)row*256 + tid;
  float t = fminf(fmaxf(x[i] + y[i], -1e6f), 1e6f);
  float s1 = t, s2 = t*t;
  #pragma unroll
  for (int off=32; off; off>>=1){ s1 += __shfl_down(s1,off); s2 += __shfl_down(s2,off); }
  if ((tid&63)==0){ red[(tid>>6)*2] = s1; red[(tid>>6)*2+1] = s2; }
  __syncthreads();
  s1 = red[0]+red[2]+red[4]+red[6];
  s2 = red[1]+red[3]+red[5]+red[7];
  float mu = s1 * (1.0f/256.0f);
  float var = fmaxf(s2 * (1.0f/256.0f) - mu*mu, 0.f);
  float rstd = rsqrtf(var + 1e-5f);
  float v = (t-mu)*rstd*g[tid] + bb[tid];
  if (out_f) out_f[i] = v;
  if (out_b) out_b[i] = f2b(v);
  if (out_pos_b) out_pos_b[i] = f2b(v + q_pos[i]);
}

__global__ void fill_u32(unsigned* p, unsigned val, int n)
{ int i = blockIdx.x*256 + threadIdx.x; if (i<n) p[i] = val; }

// ---------------------------------------------------------------------------
// Pre-gather cross-attn bias into dense biasT[b][j][q] (j = position in kidx).
// ---------------------------------------------------------------------------
__global__ __launch_bounds__(256) void bias_gather(const float* cbias, const int* kidx,
    float* biasT)
{
  int b = blockIdx.y;
  int j = blockIdx.x*8 + (threadIdx.x>>5);
  int q = threadIdx.x & 31;
  int kid = kidx[b*CROSSK_ + j];
  const float* src = cbias + (long)b*Q_*K_ + kid;
  float* dst = biasT + ((long)b*CROSSK_ + j)*200;
  for (int qq=q; qq<200; qq+=32) dst[qq] = src[(long)qq*K_];
}

// ---------------------------------------------------------------------------
// Fused MHA, flash-style with KV-split (flash-decoding). One block per
// (b, h, 64-q-tile, kv-split). Scores kept in registers; each thread
// accumulates all 32 dims for its q-row quadrant, quad-reduced via shfl.
// Bias (cross) read from dense pre-gathered biasT[b][j][q].
// ---------------------------------------------------------------------------
__global__ __launch_bounds__(256) void attn_kernel(
    const u16* Qb, int q_stride,
    const u16* KVb, int kv_stride, int k_off, int v_off, int Lk,
    const float* biasT,
    int nsplit, int chunk,
    float* opart, float* mlpart, float scale)
{
  __shared__ float Ks[64][36];
  __shared__ float Vs[64][36];
  const int b = blockIdx.z, h = blockIdx.y;
  const int split = blockIdx.x % nsplit;
  const int q0 = (blockIdx.x / nsplit) * 64;
  const int tid = threadIdx.x;
  const int cg = tid & 3, r = tid >> 2;
  const int kbeg = split*chunk;
  int kend = kbeg + chunk; if (kend > Lk) kend = Lk;

  int qr = q0 + r; if (qr > 199) qr = 199;
  float qreg[32];
  {
    const u16* qp = Qb + (long)(b*200+qr)*q_stride + h*32;
    #pragma unroll
    for (int w=0; w<4; w++){
      uint4 u = *(const uint4*)(qp + w*8);
      qreg[w*8+0]=b2f((u16)(u.x&0xffffu))*scale; qreg[w*8+1]=b2f((u16)(u.x>>16))*scale;
      qreg[w*8+2]=b2f((u16)(u.y&0xffffu))*scale; qreg[w*8+3]=b2f((u16)(u.y>>16))*scale;
      qreg[w*8+4]=b2f((u16)(u.z&0xffffu))*scale; qreg[w*8+5]=b2f((u16)(u.z>>16))*scale;
      qreg[w*8+6]=b2f((u16)(u.w&0xffffu))*scale; qreg[w*8+7]=b2f((u16)(u.w>>16))*scale;
    }
  }
  const float* bT = biasT ? biasT + ((long)b*CROSSK_)*200 + qr : nullptr;

  float o32[32];
  #pragma unroll
  for (int i=0;i<32;i++) o32[i]=0.f;
  float mrun = -3e38f, lrun = 0.f;

  const int srow = tid>>2, sc8 = (tid&3)*8;   // staging: 1 uint4 per matrix
  for (int j0=kbeg; j0<kend; j0+=64){
    int kr = j0 + srow; if (kr > kend-1) kr = kend-1;
    const long base = (long)(b*Lk + kr)*kv_stride;
    uint4 ku = *(const uint4*)(KVb + base + k_off + sc8);
    uint4 vu = *(const uint4*)(KVb + base + v_off + sc8);
    __syncthreads();   // prior tile fully consumed
    {
      float4 f0, f1;
      f0.x=b2f((u16)(ku.x&0xffffu)); f0.y=b2f((u16)(ku.x>>16)); f0.z=b2f((u16)(ku.y&0xffffu)); f0.w=b2f((u16)(ku.y>>16));
      f1.x=b2f((u16)(ku.z&0xffffu)); f1.y=b2f((u16)(ku.z>>16)); f1.z=b2f((u16)(ku.w&0xffffu)); f1.w=b2f((u16)(ku.w>>16));
      *(float4*)&Ks[srow][sc8] = f0; *(float4*)&Ks[srow][sc8+4] = f1;
      f0.x=b2f((u16)(vu.x&0xffffu)); f0.y=b2f((u16)(vu.x>>16)); f0.z=b2f((u16)(vu.y&0xffffu)); f0.w=b2f((u16)(vu.y>>16));
      f1.x=b2f((u16)(vu.z&0xffffu)); f1.y=b2f((u16)(vu.z>>16)); f1.z=b2f((u16)(vu.w&0xffffu)); f1.w=b2f((u16)(vu.w>>16));
      *(float4*)&Vs[srow][sc8] = f0; *(float4*)&Vs[srow][sc8+4] = f1;
    }
    __syncthreads();

    float sv[16];
    float mloc = -3e38f;
    #pragma unroll
    for (int jj=0;jj<16;jj++){
      const int c = cg + jj*4;
      const float4* kp = (const float4*)&Ks[c][0];
      float a = 0.f;
      #pragma unroll
      for (int dq=0;dq<8;dq++){
        float4 kv = kp[dq];
        a += qreg[dq*4+0]*kv.x + qreg[dq*4+1]*kv.y + qreg[dq*4+2]*kv.z + qreg[dq*4+3]*kv.w;
      }
      if (biasT) a += bT[(long)(j0 + c)*200];
      if (j0 + c >= kend) a = -3e38f;
      sv[jj] = a; mloc = fmaxf(mloc, a);
    }
    mloc = fmaxf(mloc, __shfl_xor(mloc,1));
    mloc = fmaxf(mloc, __shfl_xor(mloc,2));
    const float mnew = fmaxf(mrun, mloc);
    const float alpha = __expf(mrun - mnew);
    float lloc = 0.f;
    #pragma unroll
    for (int jj=0;jj<16;jj++){
      float p = (j0 + cg + jj*4 >= kend) ? 0.f : __expf(sv[jj]-mnew);
      sv[jj] = p; lloc += p;
    }
    lloc += __shfl_xor(lloc,1);
    lloc += __shfl_xor(lloc,2);
    lrun = lrun*alpha + lloc;
    #pragma unroll
    for (int i=0;i<32;i++) o32[i] *= alpha;
    #pragma unroll
    for (int jj=0;jj<16;jj++){
      const int c = cg + jj*4;
      const float p = sv[jj];
      const float4* vp = (const float4*)&Vs[c][0];
      #pragma unroll
      for (int dq=0;dq<8;dq++){
        float4 v = vp[dq];
        o32[dq*4+0] += p*v.x; o32[dq*4+1] += p*v.y; o32[dq*4+2] += p*v.z; o32[dq*4+3] += p*v.w;
      }
    }
    mrun = mnew;
  }

  #pragma unroll
  for (int d=0;d<32;d++){
    float v = o32[d];
    v += __shfl_xor(v,1);
    v += __shfl_xor(v,2);
    o32[d] = v;
  }
  if (q0 + r < 200){
    const long pbase = (((long)(b*H_+h)*nsplit + split)*200) + (q0 + r);
    float* op = opart + pbase*32;
    #pragma unroll
    for (int i=0;i<8;i++) op[cg*8+i] = o32[cg*8+i];
    if (cg==0){ mlpart[pbase*2] = mrun; mlpart[pbase*2+1] = lrun; }
  }
}

// Combine KV-split partials: out = sum_s o_s*exp(m_s-M) / sum_s l_s*exp(m_s-M)
__global__ __launch_bounds__(256) void attn_combine(const float* opart, const float* mlpart,
    int nsplit, u16* outp)
{
  int row = blockIdx.x;                 // 0..BQ_-1
  int b = row/200, qi = row%200;
  int tid = threadIdx.x;
  int h = tid>>5, d = tid&31;
  const long base = ((long)(b*H_+h)*nsplit)*200 + qi;   // + s*200 per split
  float M = -3e38f;
  for (int s=0;s<nsplit;s++) M = fmaxf(M, mlpart[(base + (long)s*200)*2]);
  float L = 0.f, acc = 0.f;
  for (int s=0;s<nsplit;s++){
    const long ix = base + (long)s*200;
    float w = __expf(mlpart[ix*2] - M);
    L   += mlpart[ix*2+1]*w;
    acc += opart[ix*32 + d]*w;
  }
  outp[(long)row*256 + h*32 + d] = f2b(acc / fmaxf(L, 1e-30f));
}

// ---------------------------------------------------------------------------
extern "C" void kernel_launch(void* const* d_in, const int* in_sizes, int n_in,
                              void* d_out, int out_size, void* d_ws, size_t ws_size,
                              hipStream_t stream)
{
  const float* q        = (const float*)d_in[0];
  const float* q_pos    = (const float*)d_in[1];
  const float* memory   = (const float*)d_in[2];
  const float* cbias    = (const float*)d_in[3];
  const float* align_wq = (const float*)d_in[4];
  const float* align_wm = (const float*)d_in[5];
  const float* gate_w1  = (const float*)d_in[6];
  const float* gate_b1  = (const float*)d_in[7];
  const float* gate_w2  = (const float*)d_in[8];
  const float* gate_b2  = (const float*)d_in[9];
  const float* cross_wq = (const float*)d_in[10];
  const float* cross_wm = (const float*)d_in[11];
  const float* sa_in_w  = (const float*)d_in[12];
  const float* sa_in_b  = (const float*)d_in[13];
  const float* sa_out_w = (const float*)d_in[14];
  const float* sa_out_b = (const float*)d_in[15];
  const float* ca_in_w  = (const float*)d_in[16];
  const float* ca_in_b  = (const float*)d_in[17];
  const float* ca_out_w = (const float*)d_in[18];
  const float* ca_out_b = (const float*)d_in[19];
  const float* ffn_w1   = (const float*)d_in[20];
  const float* ffn_b1   = (const float*)d_in[21];
  const float* ffn_w2   = (const float*)d_in[22];
  const float* ffn_b2   = (const float*)d_in[23];
  const float* n1_g = (const float*)d_in[24];
  const float* n1_b = (const float*)d_in[25];
  const float* n2_g = (const float*)d_in[26];
  const float* n2_b = (const float*)d_in[27];
  const float* n3_g = (const float*)d_in[28];
  const float* n3_b = (const float*)d_in[29];
  float* out = (float*)d_out;   // reference output dtype is fp32

  // ---- workspace layout, fitted to ws_size (deterministic per call) ----
  char* wsb = (char*)d_ws;
  size_t off = 0;
  auto alloc = [&](size_t bytes)->char*{
    char* p = wsb + off; off = (off + bytes + 255) & ~(size_t)255; return p;
  };
  const int NSPLIT = 4;   // KV splits for both attentions
  // small fixed buffers (~37 MB)
  u16*    qn_bf   = (u16*)   alloc((size_t)BQ_*D_*2);
  float*  vals96  = (float*) alloc((size_t)BQ_*96*4);
  int*    idx96   = (int*)   alloc((size_t)BQ_*96*4);
  float*  alignedv= (float*) alloc((size_t)BQ_*D_*4);
  u16*    cat_bf  = (u16*)   alloc((size_t)BQ_*512*2);
  u16*    h_bf    = (u16*)   alloc((size_t)BQ_*D_*2);
  float*  gatebuf = (float*) alloc((size_t)BQ_*D_*4);
  float*  qx      = (float*) alloc((size_t)BQ_*D_*4);
  u16*    qx_bf   = (u16*)   alloc((size_t)BQ_*D_*2);
  u16*    qk_bf   = (u16*)   alloc((size_t)BQ_*D_*2);
  u16*    qpos2_bf= (u16*)   alloc((size_t)BQ_*D_*2);
  u16*    qkv_bf  = (u16*)   alloc((size_t)BQ_*768*2);
  u16*    attO_bf = (u16*)   alloc((size_t)BQ_*D_*2);
  float*  q2      = (float*) alloc((size_t)BQ_*D_*4);
  unsigned* imp   = (unsigned*)alloc((size_t)B_*K_*4);
  int*    kidx    = (int*)   alloc((size_t)B_*CROSSK_*4);
  u16*    cq_bf   = (u16*)   alloc((size_t)BQ_*D_*2);
  u16*    f1_bf   = (u16*)   alloc((size_t)BQ_*FF_*2);
  float*  f2buf   = (float*) alloc((size_t)BQ_*D_*4);
  float*  opart   = (float*) alloc((size_t)B_*H_*NSPLIT*200*32*4);  // 6.6 MB
  float*  mlpart  = (float*) alloc((size_t)B_*H_*NSPLIT*200*2*4);   // 0.4 MB
  float*  biasT   = (float*) alloc((size_t)B_*CROSSK_*200*4);       // 6.6 MB
  u16*    wb_alwq = (u16*)   alloc((size_t)D_*D_*2);
  u16*    wb_alwm = (u16*)   alloc((size_t)D_*D_*2);
  u16*    wb_crwq = (u16*)   alloc((size_t)D_*D_*2);
  u16*    wb_crwm = (u16*)   alloc((size_t)D_*D_*2);

  // big buffers: mn (>= kvbuf size, kvbuf aliases it) and simbuf
  const size_t kv_bytes   = (size_t)B_*CROSSK_*512*2;        // 8.4 MB
  const size_t mn_full    = (size_t)BK_*D_*2;                // 67 MB
  const size_t mn_small   = (size_t)K_*D_*2;                 // 8.4 MB
  const size_t sim_full   = (size_t)BQ_*K_*4;                // 105 MB
  size_t remain = (ws_size > off) ? ws_size - off : 0;
  bool fullws = remain >= mn_full + sim_full + (1u<<20);
  size_t mn_bytes = fullws ? mn_full : (mn_small > kv_bytes ? mn_small : kv_bytes);
  int simRows;                      // rows of sim materialized at once
  if (fullws) simRows = BQ_;
  else {
    size_t left = (remain > mn_bytes + (1u<<18)) ? remain - mn_bytes - (1u<<18) : 0;
    long r = (long)(left / ((size_t)K_*4));
    simRows = (int)(r < 8 ? 8 : (r > Q_ ? Q_ : r));
  }
  u16*   mn_bf  = (u16*)  alloc(mn_bytes);
  u16*   kvbuf  = (u16*)  mn_bf;     // alias: mn dead before kvbuf is written
  float* simbuf = (float*)alloc((size_t)simRows*K_*4);

  auto gemm = [&](int af32, int bf32,
                  const void* A, long lda, long sA,
                  const void* Bm, long ldb, long sB,
                  int M, int N, int Kd,
                  const float* bias, int act,
                  float* Cf, u16* Cb, long ldc, long sC,
                  unsigned* amax, long sAmax,
                  const int* gather, long sGather, int Z){
    GArgs ga;
    ga.A=A; ga.B=Bm; ga.bias=bias; ga.Cf=Cf; ga.Cb=Cb; ga.amax=amax; ga.gather=gather;
    ga.lda=lda; ga.ldb=ldb; ga.ldc=ldc; ga.sA=sA; ga.sB=sB; ga.sC=sC;
    ga.sAmax=sAmax; ga.sGather=sGather;
    ga.M=M; ga.N=N; ga.K=Kd; ga.act=act;
    dim3 grid(N/64, (M+63)/64, Z);
    if (af32 && bf32)      gemm_bt<1,1><<<grid, 256, 0, stream>>>(ga);
    else if (af32)         gemm_bt<1,0><<<grid, 256, 0, stream>>>(ga);
    else if (bf32)         gemm_bt<0,1><<<grid, 256, 0, stream>>>(ga);
    else                   gemm_bt<0,0><<<grid, 256, 0, stream>>>(ga);
  };
  const float ascale = 0.17677669529663687f;  // 1/sqrt(32)

  // --- one-shot weight conversions (bf16) for the 4 l2norm'd projections ---
  w2b_kernel<<<32,256,0,stream>>>(align_wq, wb_alwq, D_*D_);
  w2b_kernel<<<32,256,0,stream>>>(align_wm, wb_alwm, D_*D_);
  w2b_kernel<<<32,256,0,stream>>>(cross_wq, wb_crwq, D_*D_);
  w2b_kernel<<<32,256,0,stream>>>(cross_wm, wb_crwm, D_*D_);

  // --- align: fused projection+l2norm + sim + top-96 ---
  proj_l2norm<1><<<BQ_/64,256,0,stream>>>(q, 256, wb_alwq, qn_bf, BQ_);
  if (fullws){
    proj_l2norm<1><<<BK_/64,256,0,stream>>>(memory, 256, wb_alwm, mn_bf, BK_);
    gemm(0,0, qn_bf,256,(long)200*256, mn_bf,256,(long)K_*256, 200,K_,256,
         nullptr,0, simbuf,nullptr,K_,(long)200*K_, nullptr,0, nullptr,0, B_);
    topk_kernel<<<BQ_,256,0,stream>>>(simbuf, nullptr, K_, 96, vals96, idx96);
  } else {
    for (int b=0;b<B_;b++){
      proj_l2norm<1><<<K_/64,256,0,stream>>>(memory + (size_t)b*K_*256, 256, wb_alwm, mn_bf, K_);
      for (int q0=0; q0<Q_; q0+=simRows){
        int rows = (Q_ - q0 < simRows) ? (Q_ - q0) : simRows;
        gemm(0,0, qn_bf + ((size_t)b*200+q0)*256,256,0, mn_bf,256,0, rows,K_,256,
             nullptr,0, simbuf,nullptr,K_,0, nullptr,0, nullptr,0, 1);
        topk_kernel<<<rows,256,0,stream>>>(simbuf, nullptr, K_, 96,
             vals96 + ((size_t)b*200+q0)*96, idx96 + ((size_t)b*200+q0)*96);
      }
    }
  }
  align_combine<<<BQ_,256,0,stream>>>(vals96, idx96, memory, alignedv);

  // --- gate MLP ---
  make_cat<<<BQ_,256,0,stream>>>(q, alignedv, cat_bf);
  gemm(0,1, cat_bf,512,0, gate_w1,512,0, BQ_,256,512, gate_b1,1, nullptr,h_bf,256,0, nullptr,0, nullptr,0, 1);
  gemm(0,1, h_bf,256,0, gate_w2,256,0, BQ_,256,256, gate_b2,2, gatebuf,nullptr,256,0, nullptr,0, nullptr,0, 1);
  combine_gate<<<BQ_,256,0,stream>>>(q, q_pos, alignedv, gatebuf, qx, qx_bf, qk_bf);

  // --- self attention (KV-split: 4 chunks of 64 over Lk=200) ---
  gemm(0,1, qk_bf,256,0, sa_in_w,256,0, BQ_,512,256, sa_in_b,0, nullptr,qkv_bf,768,0, nullptr,0, nullptr,0, 1);
  gemm(0,1, qx_bf,256,0, sa_in_w+512*256,256,0, BQ_,256,256, sa_in_b+512,0, nullptr,qkv_bf+512,768,0, nullptr,0, nullptr,0, 1);
  attn_kernel<<<dim3(4*NSPLIT,H_,B_),256,0,stream>>>(qkv_bf,768, qkv_bf,768,256,512,200,
      nullptr, NSPLIT,64, opart,mlpart, ascale);
  attn_combine<<<BQ_,256,0,stream>>>(opart, mlpart, NSPLIT, attO_bf);
  gemm(0,1, attO_bf,256,0, sa_out_w,256,0, BQ_,256,256, sa_out_b,0, q2,nullptr,256,0, nullptr,0, nullptr,0, 1);
  add_ln<<<BQ_,256,0,stream>>>(qx, q2, n1_g, n1_b, q_pos, qx, qx_bf, qpos2_bf);

  // --- cross-memory sparsify (importance = max over Q of sim2, then top-1024) ---
  proj_l2norm<0><<<BQ_/64,256,0,stream>>>(qx_bf, 256, wb_crwq, qn_bf, BQ_);
  fill_u32<<<(B_*K_+255)/256,256,0,stream>>>(imp, 0u, B_*K_);
  if (fullws){
    proj_l2norm<1><<<BK_/64,256,0,stream>>>(memory, 256, wb_crwm, mn_bf, BK_);
    gemm(0,0, qn_bf,256,(long)200*256, mn_bf,256,(long)K_*256, 200,K_,256,
         nullptr,0, nullptr,nullptr,0,0, imp,(long)K_, nullptr,0, B_);
  } else {
    for (int b=0;b<B_;b++){
      proj_l2norm<1><<<K_/64,256,0,stream>>>(memory + (size_t)b*K_*256, 256, wb_crwm, mn_bf, K_);
      gemm(0,0, qn_bf + (size_t)b*200*256,256,0, mn_bf,256,0, 200,K_,256,
           nullptr,0, nullptr,nullptr,0,0, imp + (size_t)b*K_,(long)K_, nullptr,0, 1);
    }
  }
  topk_kernel<<<B_,256,0,stream>>>(nullptr, imp, K_, CROSSK_, vals96 /*scratch*/, kidx);

  // --- cross attention (kvbuf aliases mn region; mn is dead now) ---
  bias_gather<<<dim3(CROSSK_/8, B_),256,0,stream>>>(cbias, kidx, biasT);
  gemm(1,1, memory,256,(long)K_*256, ca_in_w+256*256,256,0, CROSSK_,512,256,
       ca_in_b+256,0, nullptr,kvbuf,512,(long)CROSSK_*512, nullptr,0, kidx,(long)CROSSK_, B_);
  gemm(0,1, qpos2_bf,256,0, ca_in_w,256,0, BQ_,256,256, ca_in_b,0, nullptr,cq_bf,256,0, nullptr,0, nullptr,0, 1);
  attn_kernel<<<dim3(4*NSPLIT,H_,B_),256,0,stream>>>(cq_bf,256, kvbuf,512,0,256,CROSSK_,
      biasT, NSPLIT,256, opart,mlpart, ascale);
  attn_combine<<<BQ_,256,0,stream>>>(opart, mlpart, NSPLIT, attO_bf);
  gemm(0,1, attO_bf,256,0, ca_out_w,256,0, BQ_,256,256, ca_out_b,0, q2,nullptr,256,0, nullptr,0, nullptr,0, 1);
  add_ln<<<BQ_,256,0,stream>>>(qx, q2, n2_g, n2_b, nullptr, qx, qx_bf, nullptr);

  // --- FFN + final LN -> d_out (fp32) ---
  gemm(0,1, qx_bf,256,0, ffn_w1,256,0, BQ_,FF_,256, ffn_b1,1, nullptr,f1_bf,FF_,0, nullptr,0, nullptr,0, 1);
  gemm(0,1, f1_bf,FF_,0, ffn_w2,FF_,0, BQ_,256,FF_, ffn_b2,0, f2buf,nullptr,256,0, nullptr,0, nullptr,0, 1);
  add_ln<<<BQ_,256,0,stream>>>(qx, f2buf, n3_g, n3_b, nullptr, out, nullptr, nullptr);

  (void)in_sizes; (void)n_in; (void)out_size;
}